// Round 10
// baseline (430.510 us; speedup 1.0000x reference)
//
#include <hip/hip_runtime.h>
#include <math.h>

#define NEG_SLOPE 0.2f
#define CNT_SHIFT 44
#define EA_SCALE 262144.0f          // 2^18 fixed-point for edge_attr sums
#define EA_INV (1.0f / 262144.0f)
#define L1TILE 3072                 // int2 entries staged in LDS (24 KB)

__device__ __forceinline__ float lrelu(float x) { return x > 0.f ? x : NEG_SLOPE * x; }
__device__ __forceinline__ float elu1(float x) { return x > 0.f ? x : expf(x) - 1.f; }

// ---- k0p: one u64 atomic per edge: packed[d] += (1<<44) | fix18(ea) ----
__global__ void k0p(const int* __restrict__ dst, const float* __restrict__ ea,
                    unsigned long long* __restrict__ packed, int E) {
    int t = blockIdx.x * blockDim.x + threadIdx.x;
    if (t >= E) return;
    int d = dst[t];
    unsigned long long inc = (1ULL << CNT_SHIFT)
                           | (unsigned long long)__float2uint_rn(ea[t] * EA_SCALE);
    atomicAdd(&packed[d], inc);
}

// ---- kscanA: per-block inclusive scan of (cnt[i]+1); unpack cnt/asum ----
__global__ void kscanA(const unsigned long long* __restrict__ packed,
                       int* __restrict__ rowstart, int* __restrict__ bsum,
                       int* __restrict__ cntA, float* __restrict__ asumA, int N) {
    __shared__ int sm[256];
    int t = threadIdx.x;
    int i = blockIdx.x * 256 + t;
    int v = 0;
    if (i < N) {
        unsigned long long p = packed[i];
        int c = (int)(p >> CNT_SHIFT);
        cntA[i] = c;
        asumA[i] = (float)(p & ((1ULL << CNT_SHIFT) - 1)) * EA_INV;
        v = c + 1;
    }
    sm[t] = v;
    __syncthreads();
    for (int off = 1; off < 256; off <<= 1) {
        int u = (t >= off) ? sm[t - off] : 0;
        __syncthreads();
        sm[t] += u;
        __syncthreads();
    }
    if (i < N) rowstart[i] = sm[t] - v;
    if (t == 255) bsum[blockIdx.x] = sm[255];
}

__global__ void kscanB(int* __restrict__ bsum, int B) {
    __shared__ int sm[512];
    int t = threadIdx.x;
    int v = (t < B) ? bsum[t] : 0;
    sm[t] = v;
    __syncthreads();
    for (int off = 1; off < 512; off <<= 1) {
        int u = (t >= off) ? sm[t - off] : 0;
        __syncthreads();
        sm[t] += u;
        __syncthreads();
    }
    if (t < B) bsum[t] = sm[t] - v;  // exclusive block offsets
}

__global__ void kscanC(int* __restrict__ rowstart, const int* __restrict__ bsum, int N) {
    int i = blockIdx.x * blockDim.x + threadIdx.x;
    if (i < N) rowstart[i] += bsum[i >> 8];
}

// ---- kscatter: edge2[pos] = {src, ea_bits}; posA[t] = pos (coalesced);
//      self-loop slot = rowstart[d] + cnt[d], no atomic ----
__global__ void kscatter(const int* __restrict__ srcA, const int* __restrict__ dstA,
                         const float* __restrict__ ea, const float* __restrict__ asumA,
                         const int* __restrict__ cntA, const int* __restrict__ rowstart,
                         int* __restrict__ cursor, int2* __restrict__ edge2,
                         int* __restrict__ posA, int E, int Et) {
    int t = blockIdx.x * blockDim.x + threadIdx.x;
    if (t >= Et) return;
    if (t < E) {
        int d = dstA[t];
        int c = atomicAdd(&cursor[d], 1);
        int cd = cntA[d];
        int pos = rowstart[d] + min(c, cd - 1);   // clamp keeps replays in-range
        edge2[pos] = make_int2(srcA[t], __float_as_int(ea[t]));
        posA[t] = pos;
    } else {
        int d = t - E;
        int cd = cntA[d];
        int pos = rowstart[d] + cd;
        float eav = asumA[d] / fmaxf((float)cd, 1.0f);
        edge2[pos] = make_int2(d, __float_as_int(eav));
    }
}

// ---- kL1: LDS-tiled CSR consumption. Block = 128 consecutive nodes x 2 heads. ----
__global__ void __launch_bounds__(256, 3)
kL1(const float* __restrict__ x, const int2* __restrict__ edge2,
    const int* __restrict__ rowst, const int* __restrict__ cntA,
    const float* __restrict__ Wl, const float* __restrict__ bl,
    const float* __restrict__ Wr, const float* __restrict__ br,
    const float* __restrict__ We, const float* __restrict__ att,
    float* __restrict__ dstat, int N, int Et) {
    __shared__ float sW[7][64];  // wl0, wl1, we, att, wr0, wr1, (bl+br)
    __shared__ int2 sTile[L1TILE];
    if (threadIdx.x < 64) {
        int d = threadIdx.x;
        sW[0][d] = Wl[d];  sW[1][d] = Wl[64 + d];
        sW[2][d] = We[d];  sW[3][d] = att[d];
        sW[4][d] = Wr[d];  sW[5][d] = Wr[64 + d];
        sW[6][d] = bl[d] + br[d];
    }

    int n0 = blockIdx.x * 128;
    int nEnd = min(n0 + 128, N);
    int n = n0 + (threadIdx.x >> 1), h = threadIdx.x & 1;
    bool valid = (n < N);
    int base = h * 32;

    int eStart = rowst[n0];
    int eEnd = (nEnd < N) ? rowst[nEnd] : Et;
    int myStart = 0, myEnd = 0;
    float2 xd = make_float2(0.f, 0.f);
    if (valid) {
        myStart = rowst[n];
        myEnd = myStart + cntA[n] + 1;
        xd = ((const float2*)x)[n];
    }
    __syncthreads();   // sW ready

    float dstp[32];
    #pragma unroll
    for (int c = 0; c < 32; ++c) {
        int dc = base + c;
        dstp[c] = xd.x * sW[4][dc] + xd.y * sW[5][dc] + sW[6][dc];
    }

    float pd = 0.f, pa = 0.f, pb = 0.f;
    for (int tb = eStart; tb < eEnd; tb += L1TILE) {
        int tileLen = min(L1TILE, eEnd - tb);
        __syncthreads();   // previous tile fully consumed
        for (int j = threadIdx.x; j < tileLen; j += 256) sTile[j] = edge2[tb + j];
        __syncthreads();
        int lo = max(myStart, tb), hi = min(myEnd, tb + tileLen);
        for (int e = lo; e < hi; ++e) {
            int2 e4 = sTile[e - tb];
            float2 xs = ((const float2*)x)[e4.x];
            float eav = __int_as_float(e4.y);
            float l = 0.f;
            #pragma unroll
            for (int c = 0; c < 32; ++c) {
                int dc = base + c;
                float m = dstp[c] + xs.x * sW[0][dc] + xs.y * sW[1][dc] + eav * sW[2][dc];
                l += lrelu(m) * sW[3][dc];
            }
            float ev = expf(l);
            pd += ev; pa += ev * xs.x; pb += ev * xs.y;
        }
    }
    if (valid) {
        dstat[(size_t)n * 6 + h]     = pd;
        dstat[(size_t)n * 6 + 2 + h] = pa;
        dstat[(size_t)n * 6 + 4 + h] = pb;
    }
}

// ---- k3a: reconstruct h = agg/denom + bias1 + skip; BN partials ----
__global__ void k3a(const float* __restrict__ x, const float* __restrict__ dstat,
                    const float* __restrict__ Wl, const float* __restrict__ bl,
                    const float* __restrict__ bias1,
                    const float* __restrict__ skW, const float* __restrict__ skb,
                    float* __restrict__ hout, float* __restrict__ partial, int N) {
    __shared__ float sv[256], sq[256];
    size_t total = (size_t)N * 64;
    size_t stride = (size_t)gridDim.x * blockDim.x;
    float s = 0.f, q = 0.f;
    for (size_t idx = (size_t)blockIdx.x * blockDim.x + threadIdx.x; idx < total; idx += stride) {
        int n = (int)(idx >> 6), d = (int)(idx & 63), h2 = d >> 5;
        const float* ps = &dstat[(size_t)n * 6];
        float den = ps[h2], t0 = ps[2 + h2], t1 = ps[4 + h2];
        float agg = t0 * Wl[d] + t1 * Wl[64 + d] + den * bl[d];
        float hv = agg / (den + 1e-16f) + bias1[d]
                 + x[2 * n] * skW[d] + x[2 * n + 1] * skW[64 + d] + skb[d];
        hout[idx] = hv;
        s += hv; q += hv * hv;
    }
    sv[threadIdx.x] = s; sq[threadIdx.x] = q;
    __syncthreads();
    if (threadIdx.x < 64) {
        float a = sv[threadIdx.x] + sv[threadIdx.x + 64] + sv[threadIdx.x + 128] + sv[threadIdx.x + 192];
        float b = sq[threadIdx.x] + sq[threadIdx.x + 64] + sq[threadIdx.x + 128] + sq[threadIdx.x + 192];
        partial[(size_t)blockIdx.x * 128 + threadIdx.x] = a;
        partial[(size_t)blockIdx.x * 128 + 64 + threadIdx.x] = b;
    }
}

// ---- Kred: reduce per-block BN partials ----
__global__ void kred(const float* __restrict__ partial, float* __restrict__ bnstat, int G) {
    __shared__ float sm[256];
    int c = blockIdx.x;
    float s = 0.f;
    for (int i = threadIdx.x; i < G; i += blockDim.x) s += partial[(size_t)i * 128 + c];
    sm[threadIdx.x] = s;
    __syncthreads();
    for (int off = 128; off >= 1; off >>= 1) {
        if (threadIdx.x < off) sm[threadIdx.x] += sm[threadIdx.x + off];
        __syncthreads();
    }
    if (threadIdx.x == 0) bnstat[c] = sm[0];
}

// ---- k3b: mu, rstd ----
__global__ void k3b(const float* __restrict__ bnsum, const float* __restrict__ bnsq,
                    float* __restrict__ mu, float* __restrict__ rstd, int N) {
    int d = threadIdx.x;
    float m = bnsum[d] / (float)N;
    float v = bnsq[d] / (float)N - m * m;
    mu[d] = m;
    rstd[d] = rsqrtf(v + 1e-5f);
}

// ---- k3c: BN + ELU -> xl2, xr2 (wave per node) ----
__global__ void k3c(const float* __restrict__ h, const float* __restrict__ mu,
                    const float* __restrict__ rstd, const float* __restrict__ gamma,
                    const float* __restrict__ beta,
                    const float* __restrict__ Wl, const float* __restrict__ bl,
                    const float* __restrict__ Wr, const float* __restrict__ br,
                    float* __restrict__ xl2, float* __restrict__ xr2, int N) {
    __shared__ float sh[4][64];
    int w = threadIdx.x >> 6, lane = threadIdx.x & 63;
    int n = blockIdx.x * 4 + w;
    bool valid = (n < N);
    if (valid) {
        float hv = h[(size_t)n * 64 + lane];
        hv = (hv - mu[lane]) * rstd[lane] * gamma[lane] + beta[lane];
        sh[w][lane] = elu1(hv);
    }
    __syncthreads();
    if (!valid) return;
    int c = lane & 31;
    const float* W = (lane < 32) ? Wl : Wr;
    const float* b = (lane < 32) ? bl : br;
    float acc = b[c];
    #pragma unroll
    for (int k = 0; k < 64; ++k) acc += sh[w][k] * W[k * 32 + c];
    ((lane < 32) ? xl2 : xr2)[(size_t)n * 32 + c] = acc;
}

// ---- kL2: 32 lanes per node = 4 edge-slots x 8 channel-lanes (float4/lane).
//      evS written in CSR order (coalesced); alpha produced later by gather. ----
__global__ void kL2(const float* __restrict__ xl2, const float* __restrict__ xr2,
                    const int2* __restrict__ edge2,
                    const int* __restrict__ rowst, const int* __restrict__ cntA,
                    const float* __restrict__ We, const float* __restrict__ att,
                    float* __restrict__ evS, float* __restrict__ h2,
                    float* __restrict__ denom2, int N) {
    int g = blockIdx.x * blockDim.x + threadIdx.x;
    int n = g >> 5;
    if (n >= N) return;
    int lane = g & 31;
    int slot = lane >> 3, cl = lane & 7;
    int c4 = cl * 4;
    float4 wev  = *(const float4*)(We + c4);
    float4 attv = *(const float4*)(att + c4);
    float4 xrv  = *(const float4*)(xr2 + (size_t)n * 32 + c4);
    int start = rowst[n], len = cntA[n] + 1;
    float den = 0.f;
    float4 acc = make_float4(0.f, 0.f, 0.f, 0.f);

    for (int base = 0; base < len; base += 8) {
        int iA = base + slot, iB = base + 4 + slot;
        bool aA = iA < len, aB = iB < len;
        int2 eA = edge2[start + (aA ? iA : 0)];
        int2 eB = edge2[start + (aB ? iB : 0)];
        float4 xA = *(const float4*)(xl2 + (size_t)eA.x * 32 + c4);
        float4 xB = *(const float4*)(xl2 + (size_t)eB.x * 32 + c4);
        float evA = __int_as_float(eA.y), evB = __int_as_float(eB.y);
        float pA = lrelu(xA.x + xrv.x + evA * wev.x) * attv.x
                 + lrelu(xA.y + xrv.y + evA * wev.y) * attv.y
                 + lrelu(xA.z + xrv.z + evA * wev.z) * attv.z
                 + lrelu(xA.w + xrv.w + evA * wev.w) * attv.w;
        float pB = lrelu(xB.x + xrv.x + evB * wev.x) * attv.x
                 + lrelu(xB.y + xrv.y + evB * wev.y) * attv.y
                 + lrelu(xB.z + xrv.z + evB * wev.z) * attv.z
                 + lrelu(xB.w + xrv.w + evB * wev.w) * attv.w;
        pA += __shfl_xor(pA, 1); pB += __shfl_xor(pB, 1);
        pA += __shfl_xor(pA, 2); pB += __shfl_xor(pB, 2);
        pA += __shfl_xor(pA, 4); pB += __shfl_xor(pB, 4);
        float eevA = aA ? expf(pA) : 0.f;
        float eevB = aB ? expf(pB) : 0.f;
        if (cl == 0) {
            if (aA) evS[start + iA] = eevA;
            if (aB) evS[start + iB] = eevB;
        }
        den += eevA + eevB;
        acc.x += eevA * xA.x + eevB * xB.x;
        acc.y += eevA * xA.y + eevB * xB.y;
        acc.z += eevA * xA.z + eevB * xB.z;
        acc.w += eevA * xA.w + eevB * xB.w;
    }
    // reduce across the 4 edge-slots (lane bits 3,4)
    #pragma unroll
    for (int m = 8; m <= 16; m <<= 1) {
        den   += __shfl_xor(den, m);
        acc.x += __shfl_xor(acc.x, m);
        acc.y += __shfl_xor(acc.y, m);
        acc.z += __shfl_xor(acc.z, m);
        acc.w += __shfl_xor(acc.w, m);
    }
    float inv = 1.f / (den + 1e-16f);
    if (slot == 0) {
        float4 o = make_float4(acc.x * inv, acc.y * inv, acc.z * inv, acc.w * inv);
        *(float4*)(h2 + (size_t)n * 32 + c4) = o;
    }
    if (lane == 0) denom2[n] = den;
}

// ---- k4c: alpha gather (coalesced writes; evS reads hit L2/LLC) ----
__global__ void k4c(const float* __restrict__ evS, const int* __restrict__ posA,
                    const int* __restrict__ dstA, const int* __restrict__ rowst,
                    const int* __restrict__ cntA, const float* __restrict__ denom,
                    float* __restrict__ alpha, int E, int Et) {
    int t = blockIdx.x * blockDim.x + threadIdx.x;
    if (t >= Et) return;
    float ev, den;
    if (t < E) {
        ev = evS[posA[t]];
        den = denom[dstA[t]];
    } else {
        int d = t - E;
        ev = evS[rowst[d] + cntA[d]];
        den = denom[d];
    }
    alpha[t] = ev / (den + 1e-16f);
}

// ---- k5: h2 -> +bias2 -> elu -> two streamed MLP heads -> log_softmax ----
__global__ void __launch_bounds__(256, 1)
k5(const float* __restrict__ h2, const float* __restrict__ bias2,
   const float* __restrict__ Wt1, const float* __restrict__ bt1,
   const float* __restrict__ Wt2, const float* __restrict__ bt2,
   const float* __restrict__ Wc1, const float* __restrict__ bc1,
   const float* __restrict__ Wc2, const float* __restrict__ bc2,
   float* __restrict__ out, int N) {
    __shared__ float sWt1[1024], sWc1[1024], sWt2[640], sWc2[320];
    __shared__ float sbt1[32], sbc1[32], sbt2[20], sbc2[10], sb2[32];
    for (int i = threadIdx.x; i < 1024; i += blockDim.x) { sWt1[i] = Wt1[i]; sWc1[i] = Wc1[i]; }
    for (int i = threadIdx.x; i < 640; i += blockDim.x) sWt2[i] = Wt2[i];
    for (int i = threadIdx.x; i < 320; i += blockDim.x) sWc2[i] = Wc2[i];
    if (threadIdx.x < 32) { sbt1[threadIdx.x] = bt1[threadIdx.x]; sbc1[threadIdx.x] = bc1[threadIdx.x]; sb2[threadIdx.x] = bias2[threadIdx.x]; }
    if (threadIdx.x < 20) sbt2[threadIdx.x] = bt2[threadIdx.x];
    if (threadIdx.x < 10) sbc2[threadIdx.x] = bc2[threadIdx.x];
    __syncthreads();
    int n = blockIdx.x * blockDim.x + threadIdx.x;
    if (n >= N) return;
    float h[32];
    #pragma unroll
    for (int k = 0; k < 32; ++k) h[k] = elu1(h2[(size_t)n * 32 + k] + sb2[k]);
    float lt[20], lc[10];
    #pragma unroll
    for (int o = 0; o < 20; ++o) lt[o] = sbt2[o];
    #pragma unroll
    for (int o = 0; o < 10; ++o) lc[o] = sbc2[o];
    #pragma unroll
    for (int j = 0; j < 32; ++j) {
        float at = sbt1[j], ac = sbc1[j];
        #pragma unroll
        for (int k = 0; k < 32; ++k) { at += h[k] * sWt1[k * 32 + j]; ac += h[k] * sWc1[k * 32 + j]; }
        float tj = fmaxf(at, 0.f), cj = fmaxf(ac, 0.f);
        #pragma unroll
        for (int o = 0; o < 20; ++o) lt[o] += tj * sWt2[j * 20 + o];
        #pragma unroll
        for (int o = 0; o < 10; ++o) lc[o] += cj * sWc2[j * 10 + o];
    }
    float mt = -1e30f, mc = -1e30f;
    #pragma unroll
    for (int o = 0; o < 20; ++o) mt = fmaxf(mt, lt[o]);
    #pragma unroll
    for (int o = 0; o < 10; ++o) mc = fmaxf(mc, lc[o]);
    float st = 0.f, sc = 0.f;
    #pragma unroll
    for (int o = 0; o < 20; ++o) st += expf(lt[o] - mt);
    #pragma unroll
    for (int o = 0; o < 10; ++o) sc += expf(lc[o] - mc);
    float lset = mt + logf(st);
    float lsec = mc + logf(sc);
    #pragma unroll
    for (int o = 0; o < 10; ++o) out[(size_t)n * 30 + o] = lc[o] - lsec;
    #pragma unroll
    for (int o = 0; o < 20; ++o) out[(size_t)n * 30 + 10 + o] = lt[o] - lset;
}

extern "C" void kernel_launch(void* const* d_in, const int* in_sizes, int n_in,
                              void* d_out, int out_size, void* d_ws, size_t ws_size,
                              hipStream_t stream) {
    const float* x     = (const float*)d_in[0];
    const int*   ei    = (const int*)d_in[1];
    const float* eattr = (const float*)d_in[2];
    const float* Wl1   = (const float*)d_in[3];
    const float* bl1   = (const float*)d_in[4];
    const float* Wr1   = (const float*)d_in[5];
    const float* br1   = (const float*)d_in[6];
    const float* We1   = (const float*)d_in[7];
    const float* att1  = (const float*)d_in[8];
    const float* bias1 = (const float*)d_in[9];
    const float* skW   = (const float*)d_in[10];
    const float* skb   = (const float*)d_in[11];
    const float* gamma = (const float*)d_in[12];
    const float* beta  = (const float*)d_in[13];
    const float* Wl2   = (const float*)d_in[14];
    const float* bl2   = (const float*)d_in[15];
    const float* Wr2   = (const float*)d_in[16];
    const float* br2   = (const float*)d_in[17];
    const float* We2   = (const float*)d_in[18];
    const float* att2  = (const float*)d_in[19];
    const float* bias2 = (const float*)d_in[20];
    const float* Wc1   = (const float*)d_in[21];
    const float* bc1   = (const float*)d_in[22];
    const float* Wc2   = (const float*)d_in[23];
    const float* bc2   = (const float*)d_in[24];
    const float* Wt1   = (const float*)d_in[25];
    const float* bt1   = (const float*)d_in[26];
    const float* Wt2   = (const float*)d_in[27];
    const float* bt2   = (const float*)d_in[28];

    const int N  = in_sizes[0] / 2;
    const int E  = in_sizes[1] / 2;
    const int Et = E + N;
    const int* srcA = ei;
    const int* dstA = ei + E;
    const int G3 = 1024;
    const int B  = (N + 255) / 256;

    // workspace carve
    char* p = (char*)d_ws;
    unsigned long long* packed = (unsigned long long*)p; p += (size_t)N * 8;
    int*   cursor = (int*)p;   p += (size_t)N * 4;
    int2*  edge2  = (int2*)p;  p += (size_t)Et * 8;
    int*   posA   = (int*)p;   p += (size_t)E * 4;
    float* hbuf   = (float*)p; p += (size_t)N * 64 * 4;   // h rows; reused as h2 (N*32)
    float* xl2    = (float*)p; p += (size_t)N * 32 * 4;
    float* xr2    = (float*)p; p += (size_t)N * 32 * 4;
    float* evS    = (float*)p; p += (size_t)Et * 4;
    float* dstat  = (float*)p; p += (size_t)N * 6 * 4;
    int*   cntA   = (int*)p;   p += (size_t)N * 4;
    float* asumA  = (float*)p; p += (size_t)N * 4;
    int*   rowst  = (int*)p;   p += (size_t)N * 4;
    int*   bsum   = (int*)p;   p += 512 * 4;
    float* partial= (float*)p; p += (size_t)G3 * 128 * 4;
    float* bnstat = (float*)p; p += 128 * 4;
    float* mu     = (float*)p; p += 64 * 4;
    float* rstd   = (float*)p; p += 64 * 4;
    float* denom2 = (float*)p; p += (size_t)N * 4;
    float* h2     = hbuf;

    float* outMain  = (float*)d_out;
    float* outAlpha = outMain + (size_t)N * 30;

    // ---- CSR build (atomic-light) ----
    hipMemsetAsync(packed, 0, (size_t)N * 12, stream);    // packed + cursor
    k0p<<<(E + 255) / 256, 256, 0, stream>>>(dstA, eattr, packed, E);
    kscanA<<<B, 256, 0, stream>>>(packed, rowst, bsum, cntA, asumA, N);
    kscanB<<<1, 512, 0, stream>>>(bsum, B);
    kscanC<<<B, 256, 0, stream>>>(rowst, bsum, N);
    kscatter<<<(Et + 255) / 256, 256, 0, stream>>>(srcA, dstA, eattr, asumA, cntA,
                                                   rowst, cursor, edge2, posA, E, Et);

    // ---- layer 1 (LDS-tiled gather, zero atomics) ----
    kL1<<<(N + 127) / 128, 256, 0, stream>>>(x, edge2, rowst, cntA,
                                             Wl1, bl1, Wr1, br1, We1, att1,
                                             dstat, N, Et);

    // ---- node reconstruction + skip + BN ----
    k3a<<<G3, 256, 0, stream>>>(x, dstat, Wl1, bl1, bias1, skW, skb, hbuf, partial, N);
    kred<<<128, 256, 0, stream>>>(partial, bnstat, G3);
    k3b<<<1, 64, 0, stream>>>(bnstat, bnstat + 64, mu, rstd, N);
    k3c<<<(N + 3) / 4, 256, 0, stream>>>(hbuf, mu, rstd, gamma, beta,
                                         Wl2, bl2, Wr2, br2, xl2, xr2, N);

    // ---- layer 2 (gather, zero atomics, coalesced evS) ----
    kL2<<<((size_t)N * 32 + 255) / 256, 256, 0, stream>>>(xl2, xr2, edge2, rowst, cntA,
                                                          We2, att2, evS, h2, denom2, N);
    k4c<<<(Et + 255) / 256, 256, 0, stream>>>(evS, posA, dstA, rowst, cntA, denom2,
                                              outAlpha, E, Et);

    // ---- heads ----
    k5<<<(N + 255) / 256, 256, 0, stream>>>(h2, bias2, Wt1, bt1, Wt2, bt2,
                                            Wc1, bc1, Wc2, bc2, outMain, N);
    (void)n_in; (void)out_size; (void)ws_size;
}

// Round 11
// 422.931 us; speedup vs baseline: 1.0179x; 1.0179x over previous
//
#include <hip/hip_runtime.h>
#include <math.h>

#define NEG_SLOPE 0.2f
#define CNT_SHIFT 44
#define EA_SCALE 262144.0f          // 2^18 fixed-point for edge_attr sums
#define EA_INV (1.0f / 262144.0f)

__device__ __forceinline__ float lrelu(float x) { return x > 0.f ? x : NEG_SLOPE * x; }
__device__ __forceinline__ float elu1(float x) { return x > 0.f ? x : expf(x) - 1.f; }

// ---- k0p: one u64 atomic per edge: packed[d] += (1<<44) | fix18(ea) ----
__global__ void k0p(const int* __restrict__ dst, const float* __restrict__ ea,
                    unsigned long long* __restrict__ packed, int E) {
    int t = blockIdx.x * blockDim.x + threadIdx.x;
    if (t >= E) return;
    int d = dst[t];
    unsigned long long inc = (1ULL << CNT_SHIFT)
                           | (unsigned long long)__float2uint_rn(ea[t] * EA_SCALE);
    atomicAdd(&packed[d], inc);
}

// ---- kscanA: per-block inclusive scan of (cnt[i]+1); unpack cnt/asum ----
__global__ void kscanA(const unsigned long long* __restrict__ packed,
                       int* __restrict__ rowstart, int* __restrict__ bsum,
                       int* __restrict__ cntA, float* __restrict__ asumA, int N) {
    __shared__ int sm[256];
    int t = threadIdx.x;
    int i = blockIdx.x * 256 + t;
    int v = 0;
    if (i < N) {
        unsigned long long p = packed[i];
        int c = (int)(p >> CNT_SHIFT);
        cntA[i] = c;
        asumA[i] = (float)(p & ((1ULL << CNT_SHIFT) - 1)) * EA_INV;
        v = c + 1;
    }
    sm[t] = v;
    __syncthreads();
    for (int off = 1; off < 256; off <<= 1) {
        int u = (t >= off) ? sm[t - off] : 0;
        __syncthreads();
        sm[t] += u;
        __syncthreads();
    }
    if (i < N) rowstart[i] = sm[t] - v;
    if (t == 255) bsum[blockIdx.x] = sm[255];
}

__global__ void kscanB(int* __restrict__ bsum, int B) {
    __shared__ int sm[512];
    int t = threadIdx.x;
    int v = (t < B) ? bsum[t] : 0;
    sm[t] = v;
    __syncthreads();
    for (int off = 1; off < 512; off <<= 1) {
        int u = (t >= off) ? sm[t - off] : 0;
        __syncthreads();
        sm[t] += u;
        __syncthreads();
    }
    if (t < B) bsum[t] = sm[t] - v;  // exclusive block offsets
}

__global__ void kscanC(int* __restrict__ rowstart, const int* __restrict__ bsum, int N) {
    int i = blockIdx.x * blockDim.x + threadIdx.x;
    if (i < N) rowstart[i] += bsum[i >> 8];
}

// ---- kscatter: edge2[pos] = {src, ea_bits}; posA[t] = pos (coalesced);
//      self-loop slot = rowstart[d] + cnt[d], no atomic ----
__global__ void kscatter(const int* __restrict__ srcA, const int* __restrict__ dstA,
                         const float* __restrict__ ea, const float* __restrict__ asumA,
                         const int* __restrict__ cntA, const int* __restrict__ rowstart,
                         int* __restrict__ cursor, int2* __restrict__ edge2,
                         int* __restrict__ posA, int E, int Et) {
    int t = blockIdx.x * blockDim.x + threadIdx.x;
    if (t >= Et) return;
    if (t < E) {
        int d = dstA[t];
        int c = atomicAdd(&cursor[d], 1);
        int cd = cntA[d];
        int pos = rowstart[d] + min(c, cd - 1);   // clamp keeps replays in-range
        edge2[pos] = make_int2(srcA[t], __float_as_int(ea[t]));
        posA[t] = pos;
    } else {
        int d = t - E;
        int cd = cntA[d];
        int pos = rowstart[d] + cd;
        float eav = asumA[d] / fmaxf((float)cd, 1.0f);
        edge2[pos] = make_int2(d, __float_as_int(eav));
    }
}

// ---- kL1: one WAVE per node: 64 lanes = 2 heads x 4 edge-slots x 8 channel-lanes
//      (float4 channels/lane). Weights + dst-projection in registers; no LDS,
//      no divergence, 8 edges in flight (A/B unroll). Zero atomics. ----
__global__ void kL1(const float* __restrict__ x, const int2* __restrict__ edge2,
                    const int* __restrict__ rowst, const int* __restrict__ cntA,
                    const float* __restrict__ Wl, const float* __restrict__ bl,
                    const float* __restrict__ Wr, const float* __restrict__ br,
                    const float* __restrict__ We, const float* __restrict__ att,
                    float* __restrict__ dstat, int N) {
    int n = blockIdx.x * 4 + (threadIdx.x >> 6);
    if (n >= N) return;
    int lane = threadIdx.x & 63;
    int h = lane >> 5, lane5 = lane & 31;
    int slot = lane5 >> 3, cl = lane5 & 7;
    int dc = h * 32 + cl * 4;

    float4 wl0 = *(const float4*)(Wl + dc);
    float4 wl1 = *(const float4*)(Wl + 64 + dc);
    float4 wev = *(const float4*)(We + dc);
    float4 atv = *(const float4*)(att + dc);
    float4 wr0 = *(const float4*)(Wr + dc);
    float4 wr1 = *(const float4*)(Wr + 64 + dc);
    float4 bl4 = *(const float4*)(bl + dc);
    float4 br4 = *(const float4*)(br + dc);
    float2 xd = ((const float2*)x)[n];
    float4 dst4;
    dst4.x = xd.x * wr0.x + xd.y * wr1.x + bl4.x + br4.x;
    dst4.y = xd.x * wr0.y + xd.y * wr1.y + bl4.y + br4.y;
    dst4.z = xd.x * wr0.z + xd.y * wr1.z + bl4.z + br4.z;
    dst4.w = xd.x * wr0.w + xd.y * wr1.w + bl4.w + br4.w;

    int start = rowst[n], len = cntA[n] + 1;
    float pd = 0.f, pa = 0.f, pb = 0.f;
    for (int base = 0; base < len; base += 8) {
        int iA = base + slot, iB = base + 4 + slot;
        bool aA = iA < len, aB = iB < len;
        int2 eA = edge2[start + (aA ? iA : len - 1)];
        int2 eB = edge2[start + (aB ? iB : len - 1)];
        float2 xsA = ((const float2*)x)[eA.x];
        float2 xsB = ((const float2*)x)[eB.x];
        float evA = __int_as_float(eA.y), evB = __int_as_float(eB.y);
        float pA = lrelu(dst4.x + xsA.x * wl0.x + xsA.y * wl1.x + evA * wev.x) * atv.x
                 + lrelu(dst4.y + xsA.x * wl0.y + xsA.y * wl1.y + evA * wev.y) * atv.y
                 + lrelu(dst4.z + xsA.x * wl0.z + xsA.y * wl1.z + evA * wev.z) * atv.z
                 + lrelu(dst4.w + xsA.x * wl0.w + xsA.y * wl1.w + evA * wev.w) * atv.w;
        float pB = lrelu(dst4.x + xsB.x * wl0.x + xsB.y * wl1.x + evB * wev.x) * atv.x
                 + lrelu(dst4.y + xsB.x * wl0.y + xsB.y * wl1.y + evB * wev.y) * atv.y
                 + lrelu(dst4.z + xsB.x * wl0.z + xsB.y * wl1.z + evB * wev.z) * atv.z
                 + lrelu(dst4.w + xsB.x * wl0.w + xsB.y * wl1.w + evB * wev.w) * atv.w;
        pA += __shfl_xor(pA, 1); pB += __shfl_xor(pB, 1);
        pA += __shfl_xor(pA, 2); pB += __shfl_xor(pB, 2);
        pA += __shfl_xor(pA, 4); pB += __shfl_xor(pB, 4);
        float eevA = aA ? expf(pA) : 0.f;
        float eevB = aB ? expf(pB) : 0.f;
        pd += eevA + eevB;
        pa += eevA * xsA.x + eevB * xsB.x;
        pb += eevA * xsA.y + eevB * xsB.y;
    }
    // reduce across the 4 edge-slots (lane bits 3,4; stays within head half)
    pd += __shfl_xor(pd, 8);  pa += __shfl_xor(pa, 8);  pb += __shfl_xor(pb, 8);
    pd += __shfl_xor(pd, 16); pa += __shfl_xor(pa, 16); pb += __shfl_xor(pb, 16);
    if (lane5 == 0) {
        dstat[(size_t)n * 6 + h]     = pd;
        dstat[(size_t)n * 6 + 2 + h] = pa;
        dstat[(size_t)n * 6 + 4 + h] = pb;
    }
}

// ---- k3a: reconstruct h = agg/denom + bias1 + skip; BN partials ----
__global__ void k3a(const float* __restrict__ x, const float* __restrict__ dstat,
                    const float* __restrict__ Wl, const float* __restrict__ bl,
                    const float* __restrict__ bias1,
                    const float* __restrict__ skW, const float* __restrict__ skb,
                    float* __restrict__ hout, float* __restrict__ partial, int N) {
    __shared__ float sv[256], sq[256];
    size_t total = (size_t)N * 64;
    size_t stride = (size_t)gridDim.x * blockDim.x;
    float s = 0.f, q = 0.f;
    for (size_t idx = (size_t)blockIdx.x * blockDim.x + threadIdx.x; idx < total; idx += stride) {
        int n = (int)(idx >> 6), d = (int)(idx & 63), h2 = d >> 5;
        const float* ps = &dstat[(size_t)n * 6];
        float den = ps[h2], t0 = ps[2 + h2], t1 = ps[4 + h2];
        float agg = t0 * Wl[d] + t1 * Wl[64 + d] + den * bl[d];
        float hv = agg / (den + 1e-16f) + bias1[d]
                 + x[2 * n] * skW[d] + x[2 * n + 1] * skW[64 + d] + skb[d];
        hout[idx] = hv;
        s += hv; q += hv * hv;
    }
    sv[threadIdx.x] = s; sq[threadIdx.x] = q;
    __syncthreads();
    if (threadIdx.x < 64) {
        float a = sv[threadIdx.x] + sv[threadIdx.x + 64] + sv[threadIdx.x + 128] + sv[threadIdx.x + 192];
        float b = sq[threadIdx.x] + sq[threadIdx.x + 64] + sq[threadIdx.x + 128] + sq[threadIdx.x + 192];
        partial[(size_t)blockIdx.x * 128 + threadIdx.x] = a;
        partial[(size_t)blockIdx.x * 128 + 64 + threadIdx.x] = b;
    }
}

// ---- Kred: reduce per-block BN partials ----
__global__ void kred(const float* __restrict__ partial, float* __restrict__ bnstat, int G) {
    __shared__ float sm[256];
    int c = blockIdx.x;
    float s = 0.f;
    for (int i = threadIdx.x; i < G; i += blockDim.x) s += partial[(size_t)i * 128 + c];
    sm[threadIdx.x] = s;
    __syncthreads();
    for (int off = 128; off >= 1; off >>= 1) {
        if (threadIdx.x < off) sm[threadIdx.x] += sm[threadIdx.x + off];
        __syncthreads();
    }
    if (threadIdx.x == 0) bnstat[c] = sm[0];
}

// ---- k3b: mu, rstd ----
__global__ void k3b(const float* __restrict__ bnsum, const float* __restrict__ bnsq,
                    float* __restrict__ mu, float* __restrict__ rstd, int N) {
    int d = threadIdx.x;
    float m = bnsum[d] / (float)N;
    float v = bnsq[d] / (float)N - m * m;
    mu[d] = m;
    rstd[d] = rsqrtf(v + 1e-5f);
}

// ---- k3c: BN + ELU -> xl2, xr2 (wave per node) ----
__global__ void k3c(const float* __restrict__ h, const float* __restrict__ mu,
                    const float* __restrict__ rstd, const float* __restrict__ gamma,
                    const float* __restrict__ beta,
                    const float* __restrict__ Wl, const float* __restrict__ bl,
                    const float* __restrict__ Wr, const float* __restrict__ br,
                    float* __restrict__ xl2, float* __restrict__ xr2, int N) {
    __shared__ float sh[4][64];
    int w = threadIdx.x >> 6, lane = threadIdx.x & 63;
    int n = blockIdx.x * 4 + w;
    bool valid = (n < N);
    if (valid) {
        float hv = h[(size_t)n * 64 + lane];
        hv = (hv - mu[lane]) * rstd[lane] * gamma[lane] + beta[lane];
        sh[w][lane] = elu1(hv);
    }
    __syncthreads();
    if (!valid) return;
    int c = lane & 31;
    const float* W = (lane < 32) ? Wl : Wr;
    const float* b = (lane < 32) ? bl : br;
    float acc = b[c];
    #pragma unroll
    for (int k = 0; k < 64; ++k) acc += sh[w][k] * W[k * 32 + c];
    ((lane < 32) ? xl2 : xr2)[(size_t)n * 32 + c] = acc;
}

// ---- kL2: 32 lanes per node = 4 edge-slots x 8 channel-lanes (float4/lane).
//      evS written in CSR order (coalesced); alpha produced later by gather. ----
__global__ void kL2(const float* __restrict__ xl2, const float* __restrict__ xr2,
                    const int2* __restrict__ edge2,
                    const int* __restrict__ rowst, const int* __restrict__ cntA,
                    const float* __restrict__ We, const float* __restrict__ att,
                    float* __restrict__ evS, float* __restrict__ h2,
                    float* __restrict__ denom2, int N) {
    int g = blockIdx.x * blockDim.x + threadIdx.x;
    int n = g >> 5;
    if (n >= N) return;
    int lane = g & 31;
    int slot = lane >> 3, cl = lane & 7;
    int c4 = cl * 4;
    float4 wev  = *(const float4*)(We + c4);
    float4 attv = *(const float4*)(att + c4);
    float4 xrv  = *(const float4*)(xr2 + (size_t)n * 32 + c4);
    int start = rowst[n], len = cntA[n] + 1;
    float den = 0.f;
    float4 acc = make_float4(0.f, 0.f, 0.f, 0.f);

    for (int base = 0; base < len; base += 8) {
        int iA = base + slot, iB = base + 4 + slot;
        bool aA = iA < len, aB = iB < len;
        int2 eA = edge2[start + (aA ? iA : 0)];
        int2 eB = edge2[start + (aB ? iB : 0)];
        float4 xA = *(const float4*)(xl2 + (size_t)eA.x * 32 + c4);
        float4 xB = *(const float4*)(xl2 + (size_t)eB.x * 32 + c4);
        float evA = __int_as_float(eA.y), evB = __int_as_float(eB.y);
        float pA = lrelu(xA.x + xrv.x + evA * wev.x) * attv.x
                 + lrelu(xA.y + xrv.y + evA * wev.y) * attv.y
                 + lrelu(xA.z + xrv.z + evA * wev.z) * attv.z
                 + lrelu(xA.w + xrv.w + evA * wev.w) * attv.w;
        float pB = lrelu(xB.x + xrv.x + evB * wev.x) * attv.x
                 + lrelu(xB.y + xrv.y + evB * wev.y) * attv.y
                 + lrelu(xB.z + xrv.z + evB * wev.z) * attv.z
                 + lrelu(xB.w + xrv.w + evB * wev.w) * attv.w;
        pA += __shfl_xor(pA, 1); pB += __shfl_xor(pB, 1);
        pA += __shfl_xor(pA, 2); pB += __shfl_xor(pB, 2);
        pA += __shfl_xor(pA, 4); pB += __shfl_xor(pB, 4);
        float eevA = aA ? expf(pA) : 0.f;
        float eevB = aB ? expf(pB) : 0.f;
        if (cl == 0) {
            if (aA) evS[start + iA] = eevA;
            if (aB) evS[start + iB] = eevB;
        }
        den += eevA + eevB;
        acc.x += eevA * xA.x + eevB * xB.x;
        acc.y += eevA * xA.y + eevB * xB.y;
        acc.z += eevA * xA.z + eevB * xB.z;
        acc.w += eevA * xA.w + eevB * xB.w;
    }
    // reduce across the 4 edge-slots (lane bits 3,4)
    #pragma unroll
    for (int m = 8; m <= 16; m <<= 1) {
        den   += __shfl_xor(den, m);
        acc.x += __shfl_xor(acc.x, m);
        acc.y += __shfl_xor(acc.y, m);
        acc.z += __shfl_xor(acc.z, m);
        acc.w += __shfl_xor(acc.w, m);
    }
    float inv = 1.f / (den + 1e-16f);
    if (slot == 0) {
        float4 o = make_float4(acc.x * inv, acc.y * inv, acc.z * inv, acc.w * inv);
        *(float4*)(h2 + (size_t)n * 32 + c4) = o;
    }
    if (lane == 0) denom2[n] = den;
}

// ---- k4c: alpha gather (coalesced writes; evS reads hit L2/LLC) ----
__global__ void k4c(const float* __restrict__ evS, const int* __restrict__ posA,
                    const int* __restrict__ dstA, const int* __restrict__ rowst,
                    const int* __restrict__ cntA, const float* __restrict__ denom,
                    float* __restrict__ alpha, int E, int Et) {
    int t = blockIdx.x * blockDim.x + threadIdx.x;
    if (t >= Et) return;
    float ev, den;
    if (t < E) {
        ev = evS[posA[t]];
        den = denom[dstA[t]];
    } else {
        int d = t - E;
        ev = evS[rowst[d] + cntA[d]];
        den = denom[d];
    }
    alpha[t] = ev / (den + 1e-16f);
}

// ---- k5: h2 -> +bias2 -> elu -> two streamed MLP heads -> log_softmax ----
__global__ void __launch_bounds__(256, 1)
k5(const float* __restrict__ h2, const float* __restrict__ bias2,
   const float* __restrict__ Wt1, const float* __restrict__ bt1,
   const float* __restrict__ Wt2, const float* __restrict__ bt2,
   const float* __restrict__ Wc1, const float* __restrict__ bc1,
   const float* __restrict__ Wc2, const float* __restrict__ bc2,
   float* __restrict__ out, int N) {
    __shared__ float sWt1[1024], sWc1[1024], sWt2[640], sWc2[320];
    __shared__ float sbt1[32], sbc1[32], sbt2[20], sbc2[10], sb2[32];
    for (int i = threadIdx.x; i < 1024; i += blockDim.x) { sWt1[i] = Wt1[i]; sWc1[i] = Wc1[i]; }
    for (int i = threadIdx.x; i < 640; i += blockDim.x) sWt2[i] = Wt2[i];
    for (int i = threadIdx.x; i < 320; i += blockDim.x) sWc2[i] = Wc2[i];
    if (threadIdx.x < 32) { sbt1[threadIdx.x] = bt1[threadIdx.x]; sbc1[threadIdx.x] = bc1[threadIdx.x]; sb2[threadIdx.x] = bias2[threadIdx.x]; }
    if (threadIdx.x < 20) sbt2[threadIdx.x] = bt2[threadIdx.x];
    if (threadIdx.x < 10) sbc2[threadIdx.x] = bc2[threadIdx.x];
    __syncthreads();
    int n = blockIdx.x * blockDim.x + threadIdx.x;
    if (n >= N) return;
    float h[32];
    #pragma unroll
    for (int k = 0; k < 32; ++k) h[k] = elu1(h2[(size_t)n * 32 + k] + sb2[k]);
    float lt[20], lc[10];
    #pragma unroll
    for (int o = 0; o < 20; ++o) lt[o] = sbt2[o];
    #pragma unroll
    for (int o = 0; o < 10; ++o) lc[o] = sbc2[o];
    #pragma unroll
    for (int j = 0; j < 32; ++j) {
        float at = sbt1[j], ac = sbc1[j];
        #pragma unroll
        for (int k = 0; k < 32; ++k) { at += h[k] * sWt1[k * 32 + j]; ac += h[k] * sWc1[k * 32 + j]; }
        float tj = fmaxf(at, 0.f), cj = fmaxf(ac, 0.f);
        #pragma unroll
        for (int o = 0; o < 20; ++o) lt[o] += tj * sWt2[j * 20 + o];
        #pragma unroll
        for (int o = 0; o < 10; ++o) lc[o] += cj * sWc2[j * 10 + o];
    }
    float mt = -1e30f, mc = -1e30f;
    #pragma unroll
    for (int o = 0; o < 20; ++o) mt = fmaxf(mt, lt[o]);
    #pragma unroll
    for (int o = 0; o < 10; ++o) mc = fmaxf(mc, lc[o]);
    float st = 0.f, sc = 0.f;
    #pragma unroll
    for (int o = 0; o < 20; ++o) st += expf(lt[o] - mt);
    #pragma unroll
    for (int o = 0; o < 10; ++o) sc += expf(lc[o] - mc);
    float lset = mt + logf(st);
    float lsec = mc + logf(sc);
    #pragma unroll
    for (int o = 0; o < 10; ++o) out[(size_t)n * 30 + o] = lc[o] - lsec;
    #pragma unroll
    for (int o = 0; o < 20; ++o) out[(size_t)n * 30 + 10 + o] = lt[o] - lset;
}

extern "C" void kernel_launch(void* const* d_in, const int* in_sizes, int n_in,
                              void* d_out, int out_size, void* d_ws, size_t ws_size,
                              hipStream_t stream) {
    const float* x     = (const float*)d_in[0];
    const int*   ei    = (const int*)d_in[1];
    const float* eattr = (const float*)d_in[2];
    const float* Wl1   = (const float*)d_in[3];
    const float* bl1   = (const float*)d_in[4];
    const float* Wr1   = (const float*)d_in[5];
    const float* br1   = (const float*)d_in[6];
    const float* We1   = (const float*)d_in[7];
    const float* att1  = (const float*)d_in[8];
    const float* bias1 = (const float*)d_in[9];
    const float* skW   = (const float*)d_in[10];
    const float* skb   = (const float*)d_in[11];
    const float* gamma = (const float*)d_in[12];
    const float* beta  = (const float*)d_in[13];
    const float* Wl2   = (const float*)d_in[14];
    const float* bl2   = (const float*)d_in[15];
    const float* Wr2   = (const float*)d_in[16];
    const float* br2   = (const float*)d_in[17];
    const float* We2   = (const float*)d_in[18];
    const float* att2  = (const float*)d_in[19];
    const float* bias2 = (const float*)d_in[20];
    const float* Wc1   = (const float*)d_in[21];
    const float* bc1   = (const float*)d_in[22];
    const float* Wc2   = (const float*)d_in[23];
    const float* bc2   = (const float*)d_in[24];
    const float* Wt1   = (const float*)d_in[25];
    const float* bt1   = (const float*)d_in[26];
    const float* Wt2   = (const float*)d_in[27];
    const float* bt2   = (const float*)d_in[28];

    const int N  = in_sizes[0] / 2;
    const int E  = in_sizes[1] / 2;
    const int Et = E + N;
    const int* srcA = ei;
    const int* dstA = ei + E;
    const int G3 = 1024;
    const int B  = (N + 255) / 256;

    // workspace carve
    char* p = (char*)d_ws;
    unsigned long long* packed = (unsigned long long*)p; p += (size_t)N * 8;
    int*   cursor = (int*)p;   p += (size_t)N * 4;
    int2*  edge2  = (int2*)p;  p += (size_t)Et * 8;
    int*   posA   = (int*)p;   p += (size_t)E * 4;
    float* hbuf   = (float*)p; p += (size_t)N * 64 * 4;   // h rows; reused as h2 (N*32)
    float* xl2    = (float*)p; p += (size_t)N * 32 * 4;
    float* xr2    = (float*)p; p += (size_t)N * 32 * 4;
    float* evS    = (float*)p; p += (size_t)Et * 4;
    float* dstat  = (float*)p; p += (size_t)N * 6 * 4;
    int*   cntA   = (int*)p;   p += (size_t)N * 4;
    float* asumA  = (float*)p; p += (size_t)N * 4;
    int*   rowst  = (int*)p;   p += (size_t)N * 4;
    int*   bsum   = (int*)p;   p += 512 * 4;
    float* partial= (float*)p; p += (size_t)G3 * 128 * 4;
    float* bnstat = (float*)p; p += 128 * 4;
    float* mu     = (float*)p; p += 64 * 4;
    float* rstd   = (float*)p; p += 64 * 4;
    float* denom2 = (float*)p; p += (size_t)N * 4;
    float* h2     = hbuf;

    float* outMain  = (float*)d_out;
    float* outAlpha = outMain + (size_t)N * 30;

    // ---- CSR build (atomic-light) ----
    hipMemsetAsync(packed, 0, (size_t)N * 12, stream);    // packed + cursor
    k0p<<<(E + 255) / 256, 256, 0, stream>>>(dstA, eattr, packed, E);
    kscanA<<<B, 256, 0, stream>>>(packed, rowst, bsum, cntA, asumA, N);
    kscanB<<<1, 512, 0, stream>>>(bsum, B);
    kscanC<<<B, 256, 0, stream>>>(rowst, bsum, N);
    kscatter<<<(Et + 255) / 256, 256, 0, stream>>>(srcA, dstA, eattr, asumA, cntA,
                                                   rowst, cursor, edge2, posA, E, Et);

    // ---- layer 1 (wave-per-node, registers only, zero atomics) ----
    kL1<<<(N + 3) / 4, 256, 0, stream>>>(x, edge2, rowst, cntA,
                                         Wl1, bl1, Wr1, br1, We1, att1, dstat, N);

    // ---- node reconstruction + skip + BN ----
    k3a<<<G3, 256, 0, stream>>>(x, dstat, Wl1, bl1, bias1, skW, skb, hbuf, partial, N);
    kred<<<128, 256, 0, stream>>>(partial, bnstat, G3);
    k3b<<<1, 64, 0, stream>>>(bnstat, bnstat + 64, mu, rstd, N);
    k3c<<<(N + 3) / 4, 256, 0, stream>>>(hbuf, mu, rstd, gamma, beta,
                                         Wl2, bl2, Wr2, br2, xl2, xr2, N);

    // ---- layer 2 (gather, zero atomics, coalesced evS) ----
    kL2<<<((size_t)N * 32 + 255) / 256, 256, 0, stream>>>(xl2, xr2, edge2, rowst, cntA,
                                                          We2, att2, evS, h2, denom2, N);
    k4c<<<(Et + 255) / 256, 256, 0, stream>>>(evS, posA, dstA, rowst, cntA, denom2,
                                              outAlpha, E, Et);

    // ---- heads ----
    k5<<<(N + 255) / 256, 256, 0, stream>>>(h2, bias2, Wt1, bt1, Wt2, bt2,
                                            Wc1, bc1, Wc2, bc2, outMain, N);
    (void)n_in; (void)out_size; (void)ws_size;
}

// Round 12
// 364.417 us; speedup vs baseline: 1.1814x; 1.1606x over previous
//
#include <hip/hip_runtime.h>
#include <math.h>

#define NEG_SLOPE 0.2f
#define CNT_SHIFT 44
#define EA_SCALE 262144.0f          // 2^18 fixed-point for edge_attr sums
#define EA_INV (1.0f / 262144.0f)

__device__ __forceinline__ float lrelu(float x) { return x > 0.f ? x : NEG_SLOPE * x; }
__device__ __forceinline__ float elu1(float x) { return x > 0.f ? x : expf(x) - 1.f; }

// ---- k0p: one u64 atomic per edge: packed[d] += (1<<44) | fix18(ea).
//      The atomic's RETURN VALUE gives this edge's per-dst rank -> rankA[t]
//      (coalesced u16 write). kscatter then needs no atomics at all. ----
__global__ void k0p(const int* __restrict__ dst, const float* __restrict__ ea,
                    unsigned long long* __restrict__ packed,
                    unsigned short* __restrict__ rankA, int E) {
    int t = blockIdx.x * blockDim.x + threadIdx.x;
    if (t >= E) return;
    int d = dst[t];
    unsigned long long inc = (1ULL << CNT_SHIFT)
                           | (unsigned long long)__float2uint_rn(ea[t] * EA_SCALE);
    unsigned long long old = atomicAdd(&packed[d], inc);
    rankA[t] = (unsigned short)(old >> CNT_SHIFT);
}

// ---- kscanA: per-block inclusive scan of (cnt[i]+1); unpack cnt/asum ----
__global__ void kscanA(const unsigned long long* __restrict__ packed,
                       int* __restrict__ rowstart, int* __restrict__ bsum,
                       int* __restrict__ cntA, float* __restrict__ asumA, int N) {
    __shared__ int sm[256];
    int t = threadIdx.x;
    int i = blockIdx.x * 256 + t;
    int v = 0;
    if (i < N) {
        unsigned long long p = packed[i];
        int c = (int)(p >> CNT_SHIFT);
        cntA[i] = c;
        asumA[i] = (float)(p & ((1ULL << CNT_SHIFT) - 1)) * EA_INV;
        v = c + 1;
    }
    sm[t] = v;
    __syncthreads();
    for (int off = 1; off < 256; off <<= 1) {
        int u = (t >= off) ? sm[t - off] : 0;
        __syncthreads();
        sm[t] += u;
        __syncthreads();
    }
    if (i < N) rowstart[i] = sm[t] - v;
    if (t == 255) bsum[blockIdx.x] = sm[255];
}

__global__ void kscanB(int* __restrict__ bsum, int B) {
    __shared__ int sm[512];
    int t = threadIdx.x;
    int v = (t < B) ? bsum[t] : 0;
    sm[t] = v;
    __syncthreads();
    for (int off = 1; off < 512; off <<= 1) {
        int u = (t >= off) ? sm[t - off] : 0;
        __syncthreads();
        sm[t] += u;
        __syncthreads();
    }
    if (t < B) bsum[t] = sm[t] - v;  // exclusive block offsets
}

__global__ void kscanC(int* __restrict__ rowstart, const int* __restrict__ bsum, int N) {
    int i = blockIdx.x * blockDim.x + threadIdx.x;
    if (i < N) rowstart[i] += bsum[i >> 8];
}

// ---- kscatter: pos = rowst[d] + rank[t]; zero atomics, idempotent.
//      edge2[pos] = {src, ea_bits}; posA[t] = pos (coalesced);
//      self-loop slot = rowstart[d] + cnt[d]. ----
__global__ void kscatter(const int* __restrict__ srcA, const int* __restrict__ dstA,
                         const float* __restrict__ ea, const float* __restrict__ asumA,
                         const int* __restrict__ cntA, const int* __restrict__ rowstart,
                         const unsigned short* __restrict__ rankA,
                         int2* __restrict__ edge2, int* __restrict__ posA, int E, int Et) {
    int t = blockIdx.x * blockDim.x + threadIdx.x;
    if (t >= Et) return;
    if (t < E) {
        int d = dstA[t];
        int r = min((int)rankA[t], cntA[d] - 1);   // defensive clamp (replay safety)
        int pos = rowstart[d] + r;
        edge2[pos] = make_int2(srcA[t], __float_as_int(ea[t]));
        posA[t] = pos;
    } else {
        int d = t - E;
        int cd = cntA[d];
        int pos = rowstart[d] + cd;
        float eav = asumA[d] / fmaxf((float)cd, 1.0f);
        edge2[pos] = make_int2(d, __float_as_int(eav));
    }
}

// ---- kL1: one WAVE per node: 64 lanes = 2 heads x 4 edge-slots x 8 channel-lanes
//      (float4 channels/lane). Weights + dst-projection in registers; no LDS,
//      no divergence, 8 edges in flight (A/B unroll). Zero atomics. ----
__global__ void kL1(const float* __restrict__ x, const int2* __restrict__ edge2,
                    const int* __restrict__ rowst, const int* __restrict__ cntA,
                    const float* __restrict__ Wl, const float* __restrict__ bl,
                    const float* __restrict__ Wr, const float* __restrict__ br,
                    const float* __restrict__ We, const float* __restrict__ att,
                    float* __restrict__ dstat, int N) {
    int n = blockIdx.x * 4 + (threadIdx.x >> 6);
    if (n >= N) return;
    int lane = threadIdx.x & 63;
    int h = lane >> 5, lane5 = lane & 31;
    int slot = lane5 >> 3, cl = lane5 & 7;
    int dc = h * 32 + cl * 4;

    float4 wl0 = *(const float4*)(Wl + dc);
    float4 wl1 = *(const float4*)(Wl + 64 + dc);
    float4 wev = *(const float4*)(We + dc);
    float4 atv = *(const float4*)(att + dc);
    float4 wr0 = *(const float4*)(Wr + dc);
    float4 wr1 = *(const float4*)(Wr + 64 + dc);
    float4 bl4 = *(const float4*)(bl + dc);
    float4 br4 = *(const float4*)(br + dc);
    float2 xd = ((const float2*)x)[n];
    float4 dst4;
    dst4.x = xd.x * wr0.x + xd.y * wr1.x + bl4.x + br4.x;
    dst4.y = xd.x * wr0.y + xd.y * wr1.y + bl4.y + br4.y;
    dst4.z = xd.x * wr0.z + xd.y * wr1.z + bl4.z + br4.z;
    dst4.w = xd.x * wr0.w + xd.y * wr1.w + bl4.w + br4.w;

    int start = rowst[n], len = cntA[n] + 1;
    float pd = 0.f, pa = 0.f, pb = 0.f;
    for (int base = 0; base < len; base += 8) {
        int iA = base + slot, iB = base + 4 + slot;
        bool aA = iA < len, aB = iB < len;
        int2 eA = edge2[start + (aA ? iA : len - 1)];
        int2 eB = edge2[start + (aB ? iB : len - 1)];
        float2 xsA = ((const float2*)x)[eA.x];
        float2 xsB = ((const float2*)x)[eB.x];
        float evA = __int_as_float(eA.y), evB = __int_as_float(eB.y);
        float pA = lrelu(dst4.x + xsA.x * wl0.x + xsA.y * wl1.x + evA * wev.x) * atv.x
                 + lrelu(dst4.y + xsA.x * wl0.y + xsA.y * wl1.y + evA * wev.y) * atv.y
                 + lrelu(dst4.z + xsA.x * wl0.z + xsA.y * wl1.z + evA * wev.z) * atv.z
                 + lrelu(dst4.w + xsA.x * wl0.w + xsA.y * wl1.w + evA * wev.w) * atv.w;
        float pB = lrelu(dst4.x + xsB.x * wl0.x + xsB.y * wl1.x + evB * wev.x) * atv.x
                 + lrelu(dst4.y + xsB.x * wl0.y + xsB.y * wl1.y + evB * wev.y) * atv.y
                 + lrelu(dst4.z + xsB.x * wl0.z + xsB.y * wl1.z + evB * wev.z) * atv.z
                 + lrelu(dst4.w + xsB.x * wl0.w + xsB.y * wl1.w + evB * wev.w) * atv.w;
        pA += __shfl_xor(pA, 1); pB += __shfl_xor(pB, 1);
        pA += __shfl_xor(pA, 2); pB += __shfl_xor(pB, 2);
        pA += __shfl_xor(pA, 4); pB += __shfl_xor(pB, 4);
        float eevA = aA ? expf(pA) : 0.f;
        float eevB = aB ? expf(pB) : 0.f;
        pd += eevA + eevB;
        pa += eevA * xsA.x + eevB * xsB.x;
        pb += eevA * xsA.y + eevB * xsB.y;
    }
    // reduce across the 4 edge-slots (lane bits 3,4; stays within head half)
    pd += __shfl_xor(pd, 8);  pa += __shfl_xor(pa, 8);  pb += __shfl_xor(pb, 8);
    pd += __shfl_xor(pd, 16); pa += __shfl_xor(pa, 16); pb += __shfl_xor(pb, 16);
    if (lane5 == 0) {
        dstat[(size_t)n * 6 + h]     = pd;
        dstat[(size_t)n * 6 + 2 + h] = pa;
        dstat[(size_t)n * 6 + 4 + h] = pb;
    }
}

// ---- k3a: reconstruct h = agg/denom + bias1 + skip; BN partials ----
__global__ void k3a(const float* __restrict__ x, const float* __restrict__ dstat,
                    const float* __restrict__ Wl, const float* __restrict__ bl,
                    const float* __restrict__ bias1,
                    const float* __restrict__ skW, const float* __restrict__ skb,
                    float* __restrict__ hout, float* __restrict__ partial, int N) {
    __shared__ float sv[256], sq[256];
    size_t total = (size_t)N * 64;
    size_t stride = (size_t)gridDim.x * blockDim.x;
    float s = 0.f, q = 0.f;
    for (size_t idx = (size_t)blockIdx.x * blockDim.x + threadIdx.x; idx < total; idx += stride) {
        int n = (int)(idx >> 6), d = (int)(idx & 63), h2 = d >> 5;
        const float* ps = &dstat[(size_t)n * 6];
        float den = ps[h2], t0 = ps[2 + h2], t1 = ps[4 + h2];
        float agg = t0 * Wl[d] + t1 * Wl[64 + d] + den * bl[d];
        float hv = agg / (den + 1e-16f) + bias1[d]
                 + x[2 * n] * skW[d] + x[2 * n + 1] * skW[64 + d] + skb[d];
        hout[idx] = hv;
        s += hv; q += hv * hv;
    }
    sv[threadIdx.x] = s; sq[threadIdx.x] = q;
    __syncthreads();
    if (threadIdx.x < 64) {
        float a = sv[threadIdx.x] + sv[threadIdx.x + 64] + sv[threadIdx.x + 128] + sv[threadIdx.x + 192];
        float b = sq[threadIdx.x] + sq[threadIdx.x + 64] + sq[threadIdx.x + 128] + sq[threadIdx.x + 192];
        partial[(size_t)blockIdx.x * 128 + threadIdx.x] = a;
        partial[(size_t)blockIdx.x * 128 + 64 + threadIdx.x] = b;
    }
}

// ---- kred: reduce BN partials AND finish mu/rstd (k3b folded in; 64 blocks) ----
__global__ void kred(const float* __restrict__ partial, float* __restrict__ mu,
                     float* __restrict__ rstd, int G, int N) {
    __shared__ float s1[256], s2[256];
    int c = blockIdx.x;  // 0..63
    float a = 0.f, b = 0.f;
    for (int i = threadIdx.x; i < G; i += blockDim.x) {
        a += partial[(size_t)i * 128 + c];
        b += partial[(size_t)i * 128 + 64 + c];
    }
    s1[threadIdx.x] = a; s2[threadIdx.x] = b;
    __syncthreads();
    for (int off = 128; off >= 1; off >>= 1) {
        if (threadIdx.x < off) {
            s1[threadIdx.x] += s1[threadIdx.x + off];
            s2[threadIdx.x] += s2[threadIdx.x + off];
        }
        __syncthreads();
    }
    if (threadIdx.x == 0) {
        float m = s1[0] / (float)N;
        float v = s2[0] / (float)N - m * m;
        mu[c] = m;
        rstd[c] = rsqrtf(v + 1e-5f);
    }
}

// ---- k3c: BN + ELU -> xl2, xr2 (wave per node) ----
__global__ void k3c(const float* __restrict__ h, const float* __restrict__ mu,
                    const float* __restrict__ rstd, const float* __restrict__ gamma,
                    const float* __restrict__ beta,
                    const float* __restrict__ Wl, const float* __restrict__ bl,
                    const float* __restrict__ Wr, const float* __restrict__ br,
                    float* __restrict__ xl2, float* __restrict__ xr2, int N) {
    __shared__ float sh[4][64];
    int w = threadIdx.x >> 6, lane = threadIdx.x & 63;
    int n = blockIdx.x * 4 + w;
    bool valid = (n < N);
    if (valid) {
        float hv = h[(size_t)n * 64 + lane];
        hv = (hv - mu[lane]) * rstd[lane] * gamma[lane] + beta[lane];
        sh[w][lane] = elu1(hv);
    }
    __syncthreads();
    if (!valid) return;
    int c = lane & 31;
    const float* W = (lane < 32) ? Wl : Wr;
    const float* b = (lane < 32) ? bl : br;
    float acc = b[c];
    #pragma unroll
    for (int k = 0; k < 64; ++k) acc += sh[w][k] * W[k * 32 + c];
    ((lane < 32) ? xl2 : xr2)[(size_t)n * 32 + c] = acc;
}

// ---- kL2: 32 lanes per node = 4 edge-slots x 8 channel-lanes (float4/lane).
//      evS written in CSR order (coalesced); alpha produced later by gather. ----
__global__ void kL2(const float* __restrict__ xl2, const float* __restrict__ xr2,
                    const int2* __restrict__ edge2,
                    const int* __restrict__ rowst, const int* __restrict__ cntA,
                    const float* __restrict__ We, const float* __restrict__ att,
                    float* __restrict__ evS, float* __restrict__ h2,
                    float* __restrict__ denom2, int N) {
    int g = blockIdx.x * blockDim.x + threadIdx.x;
    int n = g >> 5;
    if (n >= N) return;
    int lane = g & 31;
    int slot = lane >> 3, cl = lane & 7;
    int c4 = cl * 4;
    float4 wev  = *(const float4*)(We + c4);
    float4 attv = *(const float4*)(att + c4);
    float4 xrv  = *(const float4*)(xr2 + (size_t)n * 32 + c4);
    int start = rowst[n], len = cntA[n] + 1;
    float den = 0.f;
    float4 acc = make_float4(0.f, 0.f, 0.f, 0.f);

    for (int base = 0; base < len; base += 8) {
        int iA = base + slot, iB = base + 4 + slot;
        bool aA = iA < len, aB = iB < len;
        int2 eA = edge2[start + (aA ? iA : 0)];
        int2 eB = edge2[start + (aB ? iB : 0)];
        float4 xA = *(const float4*)(xl2 + (size_t)eA.x * 32 + c4);
        float4 xB = *(const float4*)(xl2 + (size_t)eB.x * 32 + c4);
        float evA = __int_as_float(eA.y), evB = __int_as_float(eB.y);
        float pA = lrelu(xA.x + xrv.x + evA * wev.x) * attv.x
                 + lrelu(xA.y + xrv.y + evA * wev.y) * attv.y
                 + lrelu(xA.z + xrv.z + evA * wev.z) * attv.z
                 + lrelu(xA.w + xrv.w + evA * wev.w) * attv.w;
        float pB = lrelu(xB.x + xrv.x + evB * wev.x) * attv.x
                 + lrelu(xB.y + xrv.y + evB * wev.y) * attv.y
                 + lrelu(xB.z + xrv.z + evB * wev.z) * attv.z
                 + lrelu(xB.w + xrv.w + evB * wev.w) * attv.w;
        pA += __shfl_xor(pA, 1); pB += __shfl_xor(pB, 1);
        pA += __shfl_xor(pA, 2); pB += __shfl_xor(pB, 2);
        pA += __shfl_xor(pA, 4); pB += __shfl_xor(pB, 4);
        float eevA = aA ? expf(pA) : 0.f;
        float eevB = aB ? expf(pB) : 0.f;
        if (cl == 0) {
            if (aA) evS[start + iA] = eevA;
            if (aB) evS[start + iB] = eevB;
        }
        den += eevA + eevB;
        acc.x += eevA * xA.x + eevB * xB.x;
        acc.y += eevA * xA.y + eevB * xB.y;
        acc.z += eevA * xA.z + eevB * xB.z;
        acc.w += eevA * xA.w + eevB * xB.w;
    }
    // reduce across the 4 edge-slots (lane bits 3,4)
    #pragma unroll
    for (int m = 8; m <= 16; m <<= 1) {
        den   += __shfl_xor(den, m);
        acc.x += __shfl_xor(acc.x, m);
        acc.y += __shfl_xor(acc.y, m);
        acc.z += __shfl_xor(acc.z, m);
        acc.w += __shfl_xor(acc.w, m);
    }
    float inv = 1.f / (den + 1e-16f);
    if (slot == 0) {
        float4 o = make_float4(acc.x * inv, acc.y * inv, acc.z * inv, acc.w * inv);
        *(float4*)(h2 + (size_t)n * 32 + c4) = o;
    }
    if (lane == 0) denom2[n] = den;
}

// ---- k4c: alpha gather (coalesced writes; evS reads hit L2/LLC) ----
__global__ void k4c(const float* __restrict__ evS, const int* __restrict__ posA,
                    const int* __restrict__ dstA, const int* __restrict__ rowst,
                    const int* __restrict__ cntA, const float* __restrict__ denom,
                    float* __restrict__ alpha, int E, int Et) {
    int t = blockIdx.x * blockDim.x + threadIdx.x;
    if (t >= Et) return;
    float ev, den;
    if (t < E) {
        ev = evS[posA[t]];
        den = denom[dstA[t]];
    } else {
        int d = t - E;
        ev = evS[rowst[d] + cntA[d]];
        den = denom[d];
    }
    alpha[t] = ev / (den + 1e-16f);
}

// ---- k5: h2 -> +bias2 -> elu -> two streamed MLP heads -> log_softmax ----
__global__ void __launch_bounds__(256, 1)
k5(const float* __restrict__ h2, const float* __restrict__ bias2,
   const float* __restrict__ Wt1, const float* __restrict__ bt1,
   const float* __restrict__ Wt2, const float* __restrict__ bt2,
   const float* __restrict__ Wc1, const float* __restrict__ bc1,
   const float* __restrict__ Wc2, const float* __restrict__ bc2,
   float* __restrict__ out, int N) {
    __shared__ float sWt1[1024], sWc1[1024], sWt2[640], sWc2[320];
    __shared__ float sbt1[32], sbc1[32], sbt2[20], sbc2[10], sb2[32];
    for (int i = threadIdx.x; i < 1024; i += blockDim.x) { sWt1[i] = Wt1[i]; sWc1[i] = Wc1[i]; }
    for (int i = threadIdx.x; i < 640; i += blockDim.x) sWt2[i] = Wt2[i];
    for (int i = threadIdx.x; i < 320; i += blockDim.x) sWc2[i] = Wc2[i];
    if (threadIdx.x < 32) { sbt1[threadIdx.x] = bt1[threadIdx.x]; sbc1[threadIdx.x] = bc1[threadIdx.x]; sb2[threadIdx.x] = bias2[threadIdx.x]; }
    if (threadIdx.x < 20) sbt2[threadIdx.x] = bt2[threadIdx.x];
    if (threadIdx.x < 10) sbc2[threadIdx.x] = bc2[threadIdx.x];
    __syncthreads();
    int n = blockIdx.x * blockDim.x + threadIdx.x;
    if (n >= N) return;
    float h[32];
    #pragma unroll
    for (int k = 0; k < 32; ++k) h[k] = elu1(h2[(size_t)n * 32 + k] + sb2[k]);
    float lt[20], lc[10];
    #pragma unroll
    for (int o = 0; o < 20; ++o) lt[o] = sbt2[o];
    #pragma unroll
    for (int o = 0; o < 10; ++o) lc[o] = sbc2[o];
    #pragma unroll
    for (int j = 0; j < 32; ++j) {
        float at = sbt1[j], ac = sbc1[j];
        #pragma unroll
        for (int k = 0; k < 32; ++k) { at += h[k] * sWt1[k * 32 + j]; ac += h[k] * sWc1[k * 32 + j]; }
        float tj = fmaxf(at, 0.f), cj = fmaxf(ac, 0.f);
        #pragma unroll
        for (int o = 0; o < 20; ++o) lt[o] += tj * sWt2[j * 20 + o];
        #pragma unroll
        for (int o = 0; o < 10; ++o) lc[o] += cj * sWc2[j * 10 + o];
    }
    float mt = -1e30f, mc = -1e30f;
    #pragma unroll
    for (int o = 0; o < 20; ++o) mt = fmaxf(mt, lt[o]);
    #pragma unroll
    for (int o = 0; o < 10; ++o) mc = fmaxf(mc, lc[o]);
    float st = 0.f, sc = 0.f;
    #pragma unroll
    for (int o = 0; o < 20; ++o) st += expf(lt[o] - mt);
    #pragma unroll
    for (int o = 0; o < 10; ++o) sc += expf(lc[o] - mc);
    float lset = mt + logf(st);
    float lsec = mc + logf(sc);
    #pragma unroll
    for (int o = 0; o < 10; ++o) out[(size_t)n * 30 + o] = lc[o] - lsec;
    #pragma unroll
    for (int o = 0; o < 20; ++o) out[(size_t)n * 30 + 10 + o] = lt[o] - lset;
}

extern "C" void kernel_launch(void* const* d_in, const int* in_sizes, int n_in,
                              void* d_out, int out_size, void* d_ws, size_t ws_size,
                              hipStream_t stream) {
    const float* x     = (const float*)d_in[0];
    const int*   ei    = (const int*)d_in[1];
    const float* eattr = (const float*)d_in[2];
    const float* Wl1   = (const float*)d_in[3];
    const float* bl1   = (const float*)d_in[4];
    const float* Wr1   = (const float*)d_in[5];
    const float* br1   = (const float*)d_in[6];
    const float* We1   = (const float*)d_in[7];
    const float* att1  = (const float*)d_in[8];
    const float* bias1 = (const float*)d_in[9];
    const float* skW   = (const float*)d_in[10];
    const float* skb   = (const float*)d_in[11];
    const float* gamma = (const float*)d_in[12];
    const float* beta  = (const float*)d_in[13];
    const float* Wl2   = (const float*)d_in[14];
    const float* bl2   = (const float*)d_in[15];
    const float* Wr2   = (const float*)d_in[16];
    const float* br2   = (const float*)d_in[17];
    const float* We2   = (const float*)d_in[18];
    const float* att2  = (const float*)d_in[19];
    const float* bias2 = (const float*)d_in[20];
    const float* Wc1   = (const float*)d_in[21];
    const float* bc1   = (const float*)d_in[22];
    const float* Wc2   = (const float*)d_in[23];
    const float* bc2   = (const float*)d_in[24];
    const float* Wt1   = (const float*)d_in[25];
    const float* bt1   = (const float*)d_in[26];
    const float* Wt2   = (const float*)d_in[27];
    const float* bt2   = (const float*)d_in[28];

    const int N  = in_sizes[0] / 2;
    const int E  = in_sizes[1] / 2;
    const int Et = E + N;
    const int* srcA = ei;
    const int* dstA = ei + E;
    const int G3 = 1024;
    const int B  = (N + 255) / 256;

    // workspace carve
    char* p = (char*)d_ws;
    unsigned long long* packed = (unsigned long long*)p; p += (size_t)N * 8;
    int2*  edge2  = (int2*)p;  p += (size_t)Et * 8;
    int*   posA   = (int*)p;   p += (size_t)E * 4;
    unsigned short* rankA = (unsigned short*)p; p += (size_t)E * 2;
    float* hbuf   = (float*)p; p += (size_t)N * 64 * 4;   // h rows; reused as h2 (N*32)
    float* xl2    = (float*)p; p += (size_t)N * 32 * 4;
    float* xr2    = (float*)p; p += (size_t)N * 32 * 4;
    float* evS    = (float*)p; p += (size_t)Et * 4;
    float* dstat  = (float*)p; p += (size_t)N * 6 * 4;
    int*   cntA   = (int*)p;   p += (size_t)N * 4;
    float* asumA  = (float*)p; p += (size_t)N * 4;
    int*   rowst  = (int*)p;   p += (size_t)N * 4;
    int*   bsum   = (int*)p;   p += 512 * 4;
    float* partial= (float*)p; p += (size_t)G3 * 128 * 4;
    float* mu     = (float*)p; p += 64 * 4;
    float* rstd   = (float*)p; p += 64 * 4;
    float* denom2 = (float*)p; p += (size_t)N * 4;
    float* h2     = hbuf;

    float* outMain  = (float*)d_out;
    float* outAlpha = outMain + (size_t)N * 30;

    // ---- CSR build (ranks captured in k0p's atomic; kscatter atomic-free) ----
    hipMemsetAsync(packed, 0, (size_t)N * 8, stream);
    k0p<<<(E + 255) / 256, 256, 0, stream>>>(dstA, eattr, packed, rankA, E);
    kscanA<<<B, 256, 0, stream>>>(packed, rowst, bsum, cntA, asumA, N);
    kscanB<<<1, 512, 0, stream>>>(bsum, B);
    kscanC<<<B, 256, 0, stream>>>(rowst, bsum, N);
    kscatter<<<(Et + 255) / 256, 256, 0, stream>>>(srcA, dstA, eattr, asumA, cntA,
                                                   rowst, rankA, edge2, posA, E, Et);

    // ---- layer 1 (wave-per-node, registers only, zero atomics) ----
    kL1<<<(N + 3) / 4, 256, 0, stream>>>(x, edge2, rowst, cntA,
                                         Wl1, bl1, Wr1, br1, We1, att1, dstat, N);

    // ---- node reconstruction + skip + BN ----
    k3a<<<G3, 256, 0, stream>>>(x, dstat, Wl1, bl1, bias1, skW, skb, hbuf, partial, N);
    kred<<<64, 256, 0, stream>>>(partial, mu, rstd, G3, N);
    k3c<<<(N + 3) / 4, 256, 0, stream>>>(hbuf, mu, rstd, gamma, beta,
                                         Wl2, bl2, Wr2, br2, xl2, xr2, N);

    // ---- layer 2 (gather, zero atomics, coalesced evS) ----
    kL2<<<((size_t)N * 32 + 255) / 256, 256, 0, stream>>>(xl2, xr2, edge2, rowst, cntA,
                                                          We2, att2, evS, h2, denom2, N);
    k4c<<<(Et + 255) / 256, 256, 0, stream>>>(evS, posA, dstA, rowst, cntA, denom2,
                                              outAlpha, E, Et);

    // ---- heads ----
    k5<<<(N + 255) / 256, 256, 0, stream>>>(h2, bias2, Wt1, bt1, Wt2, bt2,
                                            Wc1, bc1, Wc2, bc2, outMain, N);
    (void)n_in; (void)out_size; (void)ws_size;
}

// Round 13
// 359.627 us; speedup vs baseline: 1.1971x; 1.0133x over previous
//
#include <hip/hip_runtime.h>
#include <math.h>

#define NEG_SLOPE 0.2f
#define CNT_SHIFT 44
#define EA_SCALE 262144.0f          // 2^18 fixed-point for edge_attr sums
#define EA_INV (1.0f / 262144.0f)

__device__ __forceinline__ float lrelu(float x) { return fmaxf(x, NEG_SLOPE * x); }
__device__ __forceinline__ float elu1(float x) { return x > 0.f ? x : __expf(x) - 1.f; }

// ---- k0p: one u64 atomic per edge: packed[d] += (1<<44) | fix18(ea).
//      The atomic's RETURN VALUE gives this edge's per-dst rank -> rankA[t]. ----
__global__ void k0p(const int* __restrict__ dst, const float* __restrict__ ea,
                    unsigned long long* __restrict__ packed,
                    unsigned short* __restrict__ rankA, int E) {
    int t = blockIdx.x * blockDim.x + threadIdx.x;
    if (t >= E) return;
    int d = dst[t];
    unsigned long long inc = (1ULL << CNT_SHIFT)
                           | (unsigned long long)__float2uint_rn(ea[t] * EA_SCALE);
    unsigned long long old = atomicAdd(&packed[d], inc);
    rankA[t] = (unsigned short)(old >> CNT_SHIFT);
}

// ---- kscanA: per-block inclusive scan of (cnt[i]+1); unpack cnt/asum ----
__global__ void kscanA(const unsigned long long* __restrict__ packed,
                       int* __restrict__ rowstart, int* __restrict__ bsum,
                       int* __restrict__ cntA, float* __restrict__ asumA, int N) {
    __shared__ int sm[256];
    int t = threadIdx.x;
    int i = blockIdx.x * 256 + t;
    int v = 0;
    if (i < N) {
        unsigned long long p = packed[i];
        int c = (int)(p >> CNT_SHIFT);
        cntA[i] = c;
        asumA[i] = (float)(p & ((1ULL << CNT_SHIFT) - 1)) * EA_INV;
        v = c + 1;
    }
    sm[t] = v;
    __syncthreads();
    for (int off = 1; off < 256; off <<= 1) {
        int u = (t >= off) ? sm[t - off] : 0;
        __syncthreads();
        sm[t] += u;
        __syncthreads();
    }
    if (i < N) rowstart[i] = sm[t] - v;
    if (t == 255) bsum[blockIdx.x] = sm[255];
}

__global__ void kscanB(int* __restrict__ bsum, int B) {
    __shared__ int sm[512];
    int t = threadIdx.x;
    int v = (t < B) ? bsum[t] : 0;
    sm[t] = v;
    __syncthreads();
    for (int off = 1; off < 512; off <<= 1) {
        int u = (t >= off) ? sm[t - off] : 0;
        __syncthreads();
        sm[t] += u;
        __syncthreads();
    }
    if (t < B) bsum[t] = sm[t] - v;  // exclusive block offsets
}

__global__ void kscanC(int* __restrict__ rowstart, const int* __restrict__ bsum, int N) {
    int i = blockIdx.x * blockDim.x + threadIdx.x;
    if (i < N) rowstart[i] += bsum[i >> 8];
}

// ---- kscatter: pos = rowst[d] + rank[t]; zero atomics, idempotent. ----
__global__ void kscatter(const int* __restrict__ srcA, const int* __restrict__ dstA,
                         const float* __restrict__ ea, const float* __restrict__ asumA,
                         const int* __restrict__ cntA, const int* __restrict__ rowstart,
                         const unsigned short* __restrict__ rankA,
                         int2* __restrict__ edge2, int* __restrict__ posA, int E, int Et) {
    int t = blockIdx.x * blockDim.x + threadIdx.x;
    if (t >= Et) return;
    if (t < E) {
        int d = dstA[t];
        int r = min((int)rankA[t], cntA[d] - 1);   // defensive clamp (replay safety)
        int pos = rowstart[d] + r;
        edge2[pos] = make_int2(srcA[t], __float_as_int(ea[t]));
        posA[t] = pos;
    } else {
        int d = t - E;
        int cd = cntA[d];
        int pos = rowstart[d] + cd;
        float eav = asumA[d] / fmaxf((float)cd, 1.0f);
        edge2[pos] = make_int2(d, __float_as_int(eav));
    }
}

// ---- kL1: one WAVE per node: 64 lanes = 2 heads x 4 edge-slots x 8 channel-lanes.
//      launch_bounds(256,4): VGPR cap 128 so the 8 weight float4s + dst4 + accs
//      stay register-resident across the edge loop (VGPR=32 before was forcing
//      per-iteration weight reloads). Zero atomics. ----
__global__ void __launch_bounds__(256, 4)
kL1(const float* __restrict__ x, const int2* __restrict__ edge2,
    const int* __restrict__ rowst, const int* __restrict__ cntA,
    const float* __restrict__ Wl, const float* __restrict__ bl,
    const float* __restrict__ Wr, const float* __restrict__ br,
    const float* __restrict__ We, const float* __restrict__ att,
    float* __restrict__ dstat, int N) {
    int n = blockIdx.x * 4 + (threadIdx.x >> 6);
    if (n >= N) return;
    int lane = threadIdx.x & 63;
    int h = lane >> 5, lane5 = lane & 31;
    int slot = lane5 >> 3, cl = lane5 & 7;
    int dc = h * 32 + cl * 4;

    float4 wl0 = *(const float4*)(Wl + dc);
    float4 wl1 = *(const float4*)(Wl + 64 + dc);
    float4 wev = *(const float4*)(We + dc);
    float4 atv = *(const float4*)(att + dc);
    float4 wr0 = *(const float4*)(Wr + dc);
    float4 wr1 = *(const float4*)(Wr + 64 + dc);
    float4 bl4 = *(const float4*)(bl + dc);
    float4 br4 = *(const float4*)(br + dc);
    float2 xd = ((const float2*)x)[n];
    float4 dst4;
    dst4.x = xd.x * wr0.x + xd.y * wr1.x + bl4.x + br4.x;
    dst4.y = xd.x * wr0.y + xd.y * wr1.y + bl4.y + br4.y;
    dst4.z = xd.x * wr0.z + xd.y * wr1.z + bl4.z + br4.z;
    dst4.w = xd.x * wr0.w + xd.y * wr1.w + bl4.w + br4.w;

    int start = rowst[n], len = cntA[n] + 1;
    float pd = 0.f, pa = 0.f, pb = 0.f;
    for (int base = 0; base < len; base += 8) {
        int iA = base + slot, iB = base + 4 + slot;
        bool aA = iA < len, aB = iB < len;
        int2 eA = edge2[start + (aA ? iA : len - 1)];
        int2 eB = edge2[start + (aB ? iB : len - 1)];
        float2 xsA = ((const float2*)x)[eA.x];
        float2 xsB = ((const float2*)x)[eB.x];
        float evA = __int_as_float(eA.y), evB = __int_as_float(eB.y);
        float pA = lrelu(dst4.x + xsA.x * wl0.x + xsA.y * wl1.x + evA * wev.x) * atv.x
                 + lrelu(dst4.y + xsA.x * wl0.y + xsA.y * wl1.y + evA * wev.y) * atv.y
                 + lrelu(dst4.z + xsA.x * wl0.z + xsA.y * wl1.z + evA * wev.z) * atv.z
                 + lrelu(dst4.w + xsA.x * wl0.w + xsA.y * wl1.w + evA * wev.w) * atv.w;
        float pB = lrelu(dst4.x + xsB.x * wl0.x + xsB.y * wl1.x + evB * wev.x) * atv.x
                 + lrelu(dst4.y + xsB.x * wl0.y + xsB.y * wl1.y + evB * wev.y) * atv.y
                 + lrelu(dst4.z + xsB.x * wl0.z + xsB.y * wl1.z + evB * wev.z) * atv.z
                 + lrelu(dst4.w + xsB.x * wl0.w + xsB.y * wl1.w + evB * wev.w) * atv.w;
        pA += __shfl_xor(pA, 1); pB += __shfl_xor(pB, 1);
        pA += __shfl_xor(pA, 2); pB += __shfl_xor(pB, 2);
        pA += __shfl_xor(pA, 4); pB += __shfl_xor(pB, 4);
        float eevA = aA ? __expf(pA) : 0.f;
        float eevB = aB ? __expf(pB) : 0.f;
        pd += eevA + eevB;
        pa += eevA * xsA.x + eevB * xsB.x;
        pb += eevA * xsA.y + eevB * xsB.y;
    }
    // reduce across the 4 edge-slots (lane bits 3,4; stays within head half)
    pd += __shfl_xor(pd, 8);  pa += __shfl_xor(pa, 8);  pb += __shfl_xor(pb, 8);
    pd += __shfl_xor(pd, 16); pa += __shfl_xor(pa, 16); pb += __shfl_xor(pb, 16);
    if (lane5 == 0) {
        dstat[(size_t)n * 6 + h]     = pd;
        dstat[(size_t)n * 6 + 2 + h] = pa;
        dstat[(size_t)n * 6 + 4 + h] = pb;
    }
}

// ---- k3a: reconstruct h = agg/denom + bias1 + skip; BN partials ----
__global__ void k3a(const float* __restrict__ x, const float* __restrict__ dstat,
                    const float* __restrict__ Wl, const float* __restrict__ bl,
                    const float* __restrict__ bias1,
                    const float* __restrict__ skW, const float* __restrict__ skb,
                    float* __restrict__ hout, float* __restrict__ partial, int N) {
    __shared__ float sv[256], sq[256];
    size_t total = (size_t)N * 64;
    size_t stride = (size_t)gridDim.x * blockDim.x;
    float s = 0.f, q = 0.f;
    for (size_t idx = (size_t)blockIdx.x * blockDim.x + threadIdx.x; idx < total; idx += stride) {
        int n = (int)(idx >> 6), d = (int)(idx & 63), h2 = d >> 5;
        const float* ps = &dstat[(size_t)n * 6];
        float den = ps[h2], t0 = ps[2 + h2], t1 = ps[4 + h2];
        float agg = t0 * Wl[d] + t1 * Wl[64 + d] + den * bl[d];
        float hv = agg / (den + 1e-16f) + bias1[d]
                 + x[2 * n] * skW[d] + x[2 * n + 1] * skW[64 + d] + skb[d];
        hout[idx] = hv;
        s += hv; q += hv * hv;
    }
    sv[threadIdx.x] = s; sq[threadIdx.x] = q;
    __syncthreads();
    if (threadIdx.x < 64) {
        float a = sv[threadIdx.x] + sv[threadIdx.x + 64] + sv[threadIdx.x + 128] + sv[threadIdx.x + 192];
        float b = sq[threadIdx.x] + sq[threadIdx.x + 64] + sq[threadIdx.x + 128] + sq[threadIdx.x + 192];
        partial[(size_t)blockIdx.x * 128 + threadIdx.x] = a;
        partial[(size_t)blockIdx.x * 128 + 64 + threadIdx.x] = b;
    }
}

// ---- kred: reduce BN partials AND finish mu/rstd (64 blocks) ----
__global__ void kred(const float* __restrict__ partial, float* __restrict__ mu,
                     float* __restrict__ rstd, int G, int N) {
    __shared__ float s1[256], s2[256];
    int c = blockIdx.x;  // 0..63
    float a = 0.f, b = 0.f;
    for (int i = threadIdx.x; i < G; i += blockDim.x) {
        a += partial[(size_t)i * 128 + c];
        b += partial[(size_t)i * 128 + 64 + c];
    }
    s1[threadIdx.x] = a; s2[threadIdx.x] = b;
    __syncthreads();
    for (int off = 128; off >= 1; off >>= 1) {
        if (threadIdx.x < off) {
            s1[threadIdx.x] += s1[threadIdx.x + off];
            s2[threadIdx.x] += s2[threadIdx.x + off];
        }
        __syncthreads();
    }
    if (threadIdx.x == 0) {
        float m = s1[0] / (float)N;
        float v = s2[0] / (float)N - m * m;
        mu[c] = m;
        rstd[c] = rsqrtf(v + 1e-5f);
    }
}

// ---- k3c: BN + ELU -> xl2, xr2 (wave per node) ----
__global__ void k3c(const float* __restrict__ h, const float* __restrict__ mu,
                    const float* __restrict__ rstd, const float* __restrict__ gamma,
                    const float* __restrict__ beta,
                    const float* __restrict__ Wl, const float* __restrict__ bl,
                    const float* __restrict__ Wr, const float* __restrict__ br,
                    float* __restrict__ xl2, float* __restrict__ xr2, int N) {
    __shared__ float sh[4][64];
    int w = threadIdx.x >> 6, lane = threadIdx.x & 63;
    int n = blockIdx.x * 4 + w;
    bool valid = (n < N);
    if (valid) {
        float hv = h[(size_t)n * 64 + lane];
        hv = (hv - mu[lane]) * rstd[lane] * gamma[lane] + beta[lane];
        sh[w][lane] = elu1(hv);
    }
    __syncthreads();
    if (!valid) return;
    int c = lane & 31;
    const float* W = (lane < 32) ? Wl : Wr;
    const float* b = (lane < 32) ? bl : br;
    float acc = b[c];
    #pragma unroll
    for (int k = 0; k < 64; ++k) acc += sh[w][k] * W[k * 32 + c];
    ((lane < 32) ? xl2 : xr2)[(size_t)n * 32 + c] = acc;
}

// ---- kL2: 32 lanes per node = 4 edge-slots x 8 channel-lanes (float4/lane).
//      launch_bounds(256,4) keeps wev/attv/xrv/acc register-resident. ----
__global__ void __launch_bounds__(256, 4)
kL2(const float* __restrict__ xl2, const float* __restrict__ xr2,
    const int2* __restrict__ edge2,
    const int* __restrict__ rowst, const int* __restrict__ cntA,
    const float* __restrict__ We, const float* __restrict__ att,
    float* __restrict__ evS, float* __restrict__ h2,
    float* __restrict__ denom2, int N) {
    int g = blockIdx.x * blockDim.x + threadIdx.x;
    int n = g >> 5;
    if (n >= N) return;
    int lane = g & 31;
    int slot = lane >> 3, cl = lane & 7;
    int c4 = cl * 4;
    float4 wev  = *(const float4*)(We + c4);
    float4 attv = *(const float4*)(att + c4);
    float4 xrv  = *(const float4*)(xr2 + (size_t)n * 32 + c4);
    int start = rowst[n], len = cntA[n] + 1;
    float den = 0.f;
    float4 acc = make_float4(0.f, 0.f, 0.f, 0.f);

    for (int base = 0; base < len; base += 8) {
        int iA = base + slot, iB = base + 4 + slot;
        bool aA = iA < len, aB = iB < len;
        int2 eA = edge2[start + (aA ? iA : 0)];
        int2 eB = edge2[start + (aB ? iB : 0)];
        float4 xA = *(const float4*)(xl2 + (size_t)eA.x * 32 + c4);
        float4 xB = *(const float4*)(xl2 + (size_t)eB.x * 32 + c4);
        float evA = __int_as_float(eA.y), evB = __int_as_float(eB.y);
        float pA = lrelu(xA.x + xrv.x + evA * wev.x) * attv.x
                 + lrelu(xA.y + xrv.y + evA * wev.y) * attv.y
                 + lrelu(xA.z + xrv.z + evA * wev.z) * attv.z
                 + lrelu(xA.w + xrv.w + evA * wev.w) * attv.w;
        float pB = lrelu(xB.x + xrv.x + evB * wev.x) * attv.x
                 + lrelu(xB.y + xrv.y + evB * wev.y) * attv.y
                 + lrelu(xB.z + xrv.z + evB * wev.z) * attv.z
                 + lrelu(xB.w + xrv.w + evB * wev.w) * attv.w;
        pA += __shfl_xor(pA, 1); pB += __shfl_xor(pB, 1);
        pA += __shfl_xor(pA, 2); pB += __shfl_xor(pB, 2);
        pA += __shfl_xor(pA, 4); pB += __shfl_xor(pB, 4);
        float eevA = aA ? __expf(pA) : 0.f;
        float eevB = aB ? __expf(pB) : 0.f;
        if (cl == 0) {
            if (aA) evS[start + iA] = eevA;
            if (aB) evS[start + iB] = eevB;
        }
        den += eevA + eevB;
        acc.x += eevA * xA.x + eevB * xB.x;
        acc.y += eevA * xA.y + eevB * xB.y;
        acc.z += eevA * xA.z + eevB * xB.z;
        acc.w += eevA * xA.w + eevB * xB.w;
    }
    // reduce across the 4 edge-slots (lane bits 3,4)
    #pragma unroll
    for (int m = 8; m <= 16; m <<= 1) {
        den   += __shfl_xor(den, m);
        acc.x += __shfl_xor(acc.x, m);
        acc.y += __shfl_xor(acc.y, m);
        acc.z += __shfl_xor(acc.z, m);
        acc.w += __shfl_xor(acc.w, m);
    }
    float inv = 1.f / (den + 1e-16f);
    if (slot == 0) {
        float4 o = make_float4(acc.x * inv, acc.y * inv, acc.z * inv, acc.w * inv);
        *(float4*)(h2 + (size_t)n * 32 + c4) = o;
    }
    if (lane == 0) denom2[n] = den;
}

// ---- k4c: alpha gather (coalesced writes; evS reads hit L2/LLC) ----
__global__ void k4c(const float* __restrict__ evS, const int* __restrict__ posA,
                    const int* __restrict__ dstA, const int* __restrict__ rowst,
                    const int* __restrict__ cntA, const float* __restrict__ denom,
                    float* __restrict__ alpha, int E, int Et) {
    int t = blockIdx.x * blockDim.x + threadIdx.x;
    if (t >= Et) return;
    float ev, den;
    if (t < E) {
        ev = evS[posA[t]];
        den = denom[dstA[t]];
    } else {
        int d = t - E;
        ev = evS[rowst[d] + cntA[d]];
        den = denom[d];
    }
    alpha[t] = ev / (den + 1e-16f);
}

// ---- k5: h2 -> +bias2 -> elu -> two streamed MLP heads -> log_softmax ----
__global__ void __launch_bounds__(256, 1)
k5(const float* __restrict__ h2, const float* __restrict__ bias2,
   const float* __restrict__ Wt1, const float* __restrict__ bt1,
   const float* __restrict__ Wt2, const float* __restrict__ bt2,
   const float* __restrict__ Wc1, const float* __restrict__ bc1,
   const float* __restrict__ Wc2, const float* __restrict__ bc2,
   float* __restrict__ out, int N) {
    __shared__ float sWt1[1024], sWc1[1024], sWt2[640], sWc2[320];
    __shared__ float sbt1[32], sbc1[32], sbt2[20], sbc2[10], sb2[32];
    for (int i = threadIdx.x; i < 1024; i += blockDim.x) { sWt1[i] = Wt1[i]; sWc1[i] = Wc1[i]; }
    for (int i = threadIdx.x; i < 640; i += blockDim.x) sWt2[i] = Wt2[i];
    for (int i = threadIdx.x; i < 320; i += blockDim.x) sWc2[i] = Wc2[i];
    if (threadIdx.x < 32) { sbt1[threadIdx.x] = bt1[threadIdx.x]; sbc1[threadIdx.x] = bc1[threadIdx.x]; sb2[threadIdx.x] = bias2[threadIdx.x]; }
    if (threadIdx.x < 20) sbt2[threadIdx.x] = bt2[threadIdx.x];
    if (threadIdx.x < 10) sbc2[threadIdx.x] = bc2[threadIdx.x];
    __syncthreads();
    int n = blockIdx.x * blockDim.x + threadIdx.x;
    if (n >= N) return;
    float h[32];
    #pragma unroll
    for (int k = 0; k < 32; ++k) h[k] = elu1(h2[(size_t)n * 32 + k] + sb2[k]);
    float lt[20], lc[10];
    #pragma unroll
    for (int o = 0; o < 20; ++o) lt[o] = sbt2[o];
    #pragma unroll
    for (int o = 0; o < 10; ++o) lc[o] = sbc2[o];
    #pragma unroll
    for (int j = 0; j < 32; ++j) {
        float at = sbt1[j], ac = sbc1[j];
        #pragma unroll
        for (int k = 0; k < 32; ++k) { at += h[k] * sWt1[k * 32 + j]; ac += h[k] * sWc1[k * 32 + j]; }
        float tj = fmaxf(at, 0.f), cj = fmaxf(ac, 0.f);
        #pragma unroll
        for (int o = 0; o < 20; ++o) lt[o] += tj * sWt2[j * 20 + o];
        #pragma unroll
        for (int o = 0; o < 10; ++o) lc[o] += cj * sWc2[j * 10 + o];
    }
    float mt = -1e30f, mc = -1e30f;
    #pragma unroll
    for (int o = 0; o < 20; ++o) mt = fmaxf(mt, lt[o]);
    #pragma unroll
    for (int o = 0; o < 10; ++o) mc = fmaxf(mc, lc[o]);
    float st = 0.f, sc = 0.f;
    #pragma unroll
    for (int o = 0; o < 20; ++o) st += __expf(lt[o] - mt);
    #pragma unroll
    for (int o = 0; o < 10; ++o) sc += __expf(lc[o] - mc);
    float lset = mt + __logf(st);
    float lsec = mc + __logf(sc);
    #pragma unroll
    for (int o = 0; o < 10; ++o) out[(size_t)n * 30 + o] = lc[o] - lsec;
    #pragma unroll
    for (int o = 0; o < 20; ++o) out[(size_t)n * 30 + 10 + o] = lt[o] - lset;
}

extern "C" void kernel_launch(void* const* d_in, const int* in_sizes, int n_in,
                              void* d_out, int out_size, void* d_ws, size_t ws_size,
                              hipStream_t stream) {
    const float* x     = (const float*)d_in[0];
    const int*   ei    = (const int*)d_in[1];
    const float* eattr = (const float*)d_in[2];
    const float* Wl1   = (const float*)d_in[3];
    const float* bl1   = (const float*)d_in[4];
    const float* Wr1   = (const float*)d_in[5];
    const float* br1   = (const float*)d_in[6];
    const float* We1   = (const float*)d_in[7];
    const float* att1  = (const float*)d_in[8];
    const float* bias1 = (const float*)d_in[9];
    const float* skW   = (const float*)d_in[10];
    const float* skb   = (const float*)d_in[11];
    const float* gamma = (const float*)d_in[12];
    const float* beta  = (const float*)d_in[13];
    const float* Wl2   = (const float*)d_in[14];
    const float* bl2   = (const float*)d_in[15];
    const float* Wr2   = (const float*)d_in[16];
    const float* br2   = (const float*)d_in[17];
    const float* We2   = (const float*)d_in[18];
    const float* att2  = (const float*)d_in[19];
    const float* bias2 = (const float*)d_in[20];
    const float* Wc1   = (const float*)d_in[21];
    const float* bc1   = (const float*)d_in[22];
    const float* Wc2   = (const float*)d_in[23];
    const float* bc2   = (const float*)d_in[24];
    const float* Wt1   = (const float*)d_in[25];
    const float* bt1   = (const float*)d_in[26];
    const float* Wt2   = (const float*)d_in[27];
    const float* bt2   = (const float*)d_in[28];

    const int N  = in_sizes[0] / 2;
    const int E  = in_sizes[1] / 2;
    const int Et = E + N;
    const int* srcA = ei;
    const int* dstA = ei + E;
    const int G3 = 1024;
    const int B  = (N + 255) / 256;

    // workspace carve
    char* p = (char*)d_ws;
    unsigned long long* packed = (unsigned long long*)p; p += (size_t)N * 8;
    int2*  edge2  = (int2*)p;  p += (size_t)Et * 8;
    int*   posA   = (int*)p;   p += (size_t)E * 4;
    unsigned short* rankA = (unsigned short*)p; p += (size_t)E * 2;
    float* hbuf   = (float*)p; p += (size_t)N * 64 * 4;   // h rows; reused as h2 (N*32)
    float* xl2    = (float*)p; p += (size_t)N * 32 * 4;
    float* xr2    = (float*)p; p += (size_t)N * 32 * 4;
    float* evS    = (float*)p; p += (size_t)Et * 4;
    float* dstat  = (float*)p; p += (size_t)N * 6 * 4;
    int*   cntA   = (int*)p;   p += (size_t)N * 4;
    float* asumA  = (float*)p; p += (size_t)N * 4;
    int*   rowst  = (int*)p;   p += (size_t)N * 4;
    int*   bsum   = (int*)p;   p += 512 * 4;
    float* partial= (float*)p; p += (size_t)G3 * 128 * 4;
    float* mu     = (float*)p; p += 64 * 4;
    float* rstd   = (float*)p; p += 64 * 4;
    float* denom2 = (float*)p; p += (size_t)N * 4;
    float* h2     = hbuf;

    float* outMain  = (float*)d_out;
    float* outAlpha = outMain + (size_t)N * 30;

    // ---- CSR build (ranks captured in k0p's atomic; kscatter atomic-free) ----
    hipMemsetAsync(packed, 0, (size_t)N * 8, stream);
    k0p<<<(E + 255) / 256, 256, 0, stream>>>(dstA, eattr, packed, rankA, E);
    kscanA<<<B, 256, 0, stream>>>(packed, rowst, bsum, cntA, asumA, N);
    kscanB<<<1, 512, 0, stream>>>(bsum, B);
    kscanC<<<B, 256, 0, stream>>>(rowst, bsum, N);
    kscatter<<<(Et + 255) / 256, 256, 0, stream>>>(srcA, dstA, eattr, asumA, cntA,
                                                   rowst, rankA, edge2, posA, E, Et);

    // ---- layer 1 (wave-per-node, registers only, zero atomics) ----
    kL1<<<(N + 3) / 4, 256, 0, stream>>>(x, edge2, rowst, cntA,
                                         Wl1, bl1, Wr1, br1, We1, att1, dstat, N);

    // ---- node reconstruction + skip + BN ----
    k3a<<<G3, 256, 0, stream>>>(x, dstat, Wl1, bl1, bias1, skW, skb, hbuf, partial, N);
    kred<<<64, 256, 0, stream>>>(partial, mu, rstd, G3, N);
    k3c<<<(N + 3) / 4, 256, 0, stream>>>(hbuf, mu, rstd, gamma, beta,
                                         Wl2, bl2, Wr2, br2, xl2, xr2, N);

    // ---- layer 2 (gather, zero atomics, coalesced evS) ----
    kL2<<<((size_t)N * 32 + 255) / 256, 256, 0, stream>>>(xl2, xr2, edge2, rowst, cntA,
                                                          We2, att2, evS, h2, denom2, N);
    k4c<<<(Et + 255) / 256, 256, 0, stream>>>(evS, posA, dstA, rowst, cntA, denom2,
                                              outAlpha, E, Et);

    // ---- heads ----
    k5<<<(N + 255) / 256, 256, 0, stream>>>(h2, bias2, Wt1, bt1, Wt2, bt2,
                                            Wc1, bc1, Wc2, bc2, outMain, N);
    (void)n_in; (void)out_size; (void)ws_size;
}